// Round 1
// baseline (15370.036 us; speedup 1.0000x reference)
//
#include <hip/hip_runtime.h>
#include <hip/hip_bf16.h>
#include <math.h>

#define S 512
#define B 2
#define D 768
#define H 12
#define DH 64
#define DI 3072
#define NL 12
#define NTOK (S * B)   // 1024

__device__ __forceinline__ float gelu_f(float x) {
  const float c = 0.7978845608028654f;  // sqrt(2/pi)
  float t = tanhf(c * (x + 0.044715f * x * x * x));
  return x * 0.5f * (1.0f + t);
}

// ---------------- embedding gather: h[t, :] = lut[inp_k[t], :] ----------------
__global__ __launch_bounds__(256) void embed_kernel(const int* __restrict__ inp_k,
                                                    const float* __restrict__ lut,
                                                    float* __restrict__ h) {
  int t = blockIdx.x;           // token = i*B + b
  int id = inp_k[t];
  for (int j = threadIdx.x; j < D; j += 256)
    h[t * D + j] = lut[(size_t)id * D + j];
}

// ---------------- positional embedding r2[j, :], j in [0, 2S) ----------------
__global__ __launch_bounds__(384) void posemb_kernel(float* __restrict__ r2) {
  int j = blockIdx.x;           // 0..1023
  int d = threadIdx.x;          // 0..383
  float pos = (float)(S - j);
  // inv_freq[d] = 10000^(-2d/D)
  float inv_freq = expf(-logf(10000.0f) * (2.0f * (float)d / (float)D));
  float x = pos * inv_freq;
  r2[j * D + d]         = sinf(x);
  r2[j * D + 384 + d]   = cosf(x);
}

// ---------------- generic f32 GEMM: C[M,N] = A[M,K] @ W + bias, opt act -------
// TRANSW=false: W is [K,N] row-major.  TRANSW=true: W is [N,K] row-major (C=A@W^T).
// ACT: 0 none, 1 gelu
template <bool TRANSW, int ACT>
__global__ __launch_bounds__(256) void gemm_f32(const float* __restrict__ A,
                                                const float* __restrict__ W,
                                                const float* __restrict__ bias,
                                                float* __restrict__ C,
                                                int M, int N, int K) {
  __shared__ float As[16][65];
  __shared__ float Ws[16][65];
  int bm = blockIdx.y * 64, bn = blockIdx.x * 64;
  int tid = threadIdx.x;
  int tx = tid & 15, ty = tid >> 4;
  float acc[4][4] = {};
  for (int kt = 0; kt < K; kt += 16) {
    {
      int m = tid >> 2;
      int k4 = (tid & 3) * 4;
      const float4 a4 = *(const float4*)&A[(size_t)(bm + m) * K + kt + k4];
      As[k4 + 0][m] = a4.x; As[k4 + 1][m] = a4.y; As[k4 + 2][m] = a4.z; As[k4 + 3][m] = a4.w;
    }
    if (!TRANSW) {
      int k = tid >> 4;
      int n4 = (tid & 15) * 4;
      const float4 w4 = *(const float4*)&W[(size_t)(kt + k) * N + bn + n4];
      Ws[k][n4 + 0] = w4.x; Ws[k][n4 + 1] = w4.y; Ws[k][n4 + 2] = w4.z; Ws[k][n4 + 3] = w4.w;
    } else {
      int n = tid >> 2;
      int k4 = (tid & 3) * 4;
      const float4 w4 = *(const float4*)&W[(size_t)(bn + n) * K + kt + k4];
      Ws[k4 + 0][n] = w4.x; Ws[k4 + 1][n] = w4.y; Ws[k4 + 2][n] = w4.z; Ws[k4 + 3][n] = w4.w;
    }
    __syncthreads();
#pragma unroll
    for (int kk = 0; kk < 16; ++kk) {
      float a[4], b[4];
#pragma unroll
      for (int i = 0; i < 4; ++i) a[i] = As[kk][ty * 4 + i];
#pragma unroll
      for (int j = 0; j < 4; ++j) b[j] = Ws[kk][tx * 4 + j];
#pragma unroll
      for (int i = 0; i < 4; ++i)
#pragma unroll
        for (int j = 0; j < 4; ++j)
          acc[i][j] = fmaf(a[i], b[j], acc[i][j]);
    }
    __syncthreads();
  }
#pragma unroll
  for (int i = 0; i < 4; ++i) {
    int row = bm + ty * 4 + i;
#pragma unroll
    for (int j = 0; j < 4; ++j) {
      int col = bn + tx * 4 + j;
      float v = acc[i][j];
      if (bias) v += bias[col];
      if (ACT == 1) v = gelu_f(v);
      C[(size_t)row * N + col] = v;
    }
  }
}

// ---------------- segment-bias ef[t, n, s] = (q + r_s_bias) . seg_embed[s,n,:] --
__global__ __launch_bounds__(256) void ef_kernel(const float* __restrict__ q,
                                                 const float* __restrict__ rsb,      // [H*DH] (layer l)
                                                 const float* __restrict__ segemb,   // [2,H,DH] (layer l)
                                                 float* __restrict__ ef) {
  int idx = blockIdx.x * 256 + threadIdx.x;   // t*24 + n*2 + s
  if (idx >= NTOK * H * 2) return;
  int s = idx & 1;
  int n = (idx >> 1) % H;
  int t = idx / (H * 2);
  float acc = 0.0f;
  const float* qp = q + (size_t)t * D + n * DH;
  const float* rp = rsb + n * DH;
  const float* sp = segemb + (s * H + n) * DH;
  for (int d = 0; d < DH; ++d)
    acc = fmaf(qp[d] + rp[d], sp[d], acc);
  ef[idx] = acc;
}

// ---------------- fused attention: scores (ac+bd+ef), mask, softmax, PV --------
__global__ __launch_bounds__(256) void attn_kernel(const float* __restrict__ q,
                                                   const float* __restrict__ k,
                                                   const float* __restrict__ v,
                                                   const float* __restrict__ kr,   // [2S, H*DH]
                                                   const float* __restrict__ ef,   // [NTOK, H, 2]
                                                   const int* __restrict__ seg_ids,    // [S,B]
                                                   const int* __restrict__ input_mask, // [S,B]
                                                   const float* __restrict__ rwb,  // [H*DH] layer l
                                                   const float* __restrict__ rrb,  // [H*DH] layer l
                                                   float* __restrict__ vec) {
  int i = blockIdx.x, b = blockIdx.y, n = blockIdx.z;
  int tid = threadIdx.x;
  __shared__ float qw[DH], qr[DH];
  __shared__ float sc[S];
  __shared__ float red[256];
  __shared__ float part[4][DH];

  int t = i * B + b;
  const float* qp = q + (size_t)t * D + n * DH;
  if (tid < DH) {
    qw[tid] = qp[tid] + rwb[n * DH + tid];
    qr[tid] = qp[tid] + rrb[n * DH + tid];
  }
  __syncthreads();

  int myseg = seg_ids[t];
  for (int j = tid; j < S; j += 256) {
    const float* kp  = k  + (size_t)(j * B + b) * D + n * DH;
    const float* krp = kr + (size_t)(S - i + j) * D + n * DH;
    float ac = 0.0f, bd = 0.0f;
    for (int d = 0; d < DH; ++d) {
      ac = fmaf(qw[d], kp[d], ac);
      bd = fmaf(qr[d], krp[d], bd);
    }
    int diff = (seg_ids[j * B + b] != myseg) ? 1 : 0;
    float e = ef[((size_t)t * H + n) * 2 + diff];
    float s = (ac + bd + e) * 0.125f - 1e30f * (float)input_mask[j * B + b];
    sc[j] = s;
  }
  __syncthreads();

  // max over 512
  float m = fmaxf(sc[tid], sc[tid + 256]);
  red[tid] = m;
  __syncthreads();
  for (int st = 128; st > 0; st >>= 1) {
    if (tid < st) red[tid] = fmaxf(red[tid], red[tid + st]);
    __syncthreads();
  }
  float mx = red[0];
  __syncthreads();

  float e0 = expf(sc[tid] - mx);
  float e1 = expf(sc[tid + 256] - mx);
  sc[tid] = e0;
  sc[tid + 256] = e1;
  red[tid] = e0 + e1;
  __syncthreads();
  for (int st = 128; st > 0; st >>= 1) {
    if (tid < st) red[tid] += red[tid + st];
    __syncthreads();
  }
  float inv = 1.0f / red[0];
  __syncthreads();

  // PV: vec[t, n, d] = sum_j p[j] * v[j,b,n,d]
  int d = tid & 63, g = tid >> 6;
  float acc = 0.0f;
  for (int j = g * 128; j < (g + 1) * 128; ++j)
    acc = fmaf(sc[j], v[(size_t)(j * B + b) * D + n * DH + d], acc);
  part[g][d] = acc;
  __syncthreads();
  if (tid < DH) {
    float r = (part[0][tid] + part[1][tid] + part[2][tid] + part[3][tid]) * inv;
    vec[(size_t)t * D + n * DH + tid] = r;
  }
}

// ---------------- residual add + layernorm (in place into h) ------------------
__global__ __launch_bounds__(256) void add_ln_kernel(const float* __restrict__ x,
                                                     float* __restrict__ h,
                                                     const float* __restrict__ g,
                                                     const float* __restrict__ bi) {
  int t = blockIdx.x;
  int tid = threadIdx.x;
  __shared__ float red[256];
  float v[3];
  float s = 0.0f;
#pragma unroll
  for (int j = 0; j < 3; ++j) {
    int c = tid + j * 256;
    v[j] = x[(size_t)t * D + c] + h[(size_t)t * D + c];
    s += v[j];
  }
  red[tid] = s;
  __syncthreads();
  for (int st = 128; st > 0; st >>= 1) {
    if (tid < st) red[tid] += red[tid + st];
    __syncthreads();
  }
  float mu = red[0] / (float)D;
  __syncthreads();
  float s2 = 0.0f;
#pragma unroll
  for (int j = 0; j < 3; ++j) {
    float dd = v[j] - mu;
    s2 += dd * dd;
  }
  red[tid] = s2;
  __syncthreads();
  for (int st = 128; st > 0; st >>= 1) {
    if (tid < st) red[tid] += red[tid + st];
    __syncthreads();
  }
  float var = red[0] / (float)D;
  float rstd = rsqrtf(var + 1e-3f);
  __syncthreads();
#pragma unroll
  for (int j = 0; j < 3; ++j) {
    int c = tid + j * 256;
    h[(size_t)t * D + c] = (v[j] - mu) * rstd * g[c] + bi[c];
  }
}

extern "C" void kernel_launch(void* const* d_in, const int* in_sizes, int n_in,
                              void* d_out, int out_size, void* d_ws, size_t ws_size,
                              hipStream_t stream) {
  const int*   inp_k      = (const int*)d_in[0];
  const int*   seg_ids    = (const int*)d_in[1];
  const int*   input_mask = (const int*)d_in[2];
  const float* lut        = (const float*)d_in[3];
  const float* Wq         = (const float*)d_in[4];
  const float* Wk         = (const float*)d_in[5];
  const float* Wv         = (const float*)d_in[6];
  const float* Wr         = (const float*)d_in[7];
  const float* Wo         = (const float*)d_in[8];
  const float* r_w_bias   = (const float*)d_in[9];
  const float* r_r_bias   = (const float*)d_in[10];
  const float* r_s_bias   = (const float*)d_in[11];
  const float* seg_embed  = (const float*)d_in[12];
  const float* ln_attn_g  = (const float*)d_in[13];
  const float* ln_attn_b  = (const float*)d_in[14];
  const float* ln_ff_g    = (const float*)d_in[15];
  const float* ln_ff_b    = (const float*)d_in[16];
  const float* ff_w1      = (const float*)d_in[17];
  const float* ff_b1      = (const float*)d_in[18];
  const float* ff_w2      = (const float*)d_in[19];
  const float* ff_b2      = (const float*)d_in[20];

  // h lives in d_out (f32 [S,B,D]); scratch in ws
  float* h  = (float*)d_out;
  float* ws = (float*)d_ws;
  const size_t TOKD = (size_t)NTOK * D;  // 786432
  float* q   = ws;            ws += TOKD;
  float* k   = ws;            ws += TOKD;
  float* v   = ws;            ws += TOKD;
  float* kr  = ws;            ws += TOKD;   // [2S, D]
  float* r2  = ws;            ws += TOKD;   // [2S, D]
  float* vec = ws;            ws += TOKD;
  float* ao  = ws;            ws += TOKD;   // attn out / ff2 out (reused)
  float* ff1 = ws;            ws += (size_t)NTOK * DI;
  float* ef  = ws;            ws += (size_t)NTOK * H * 2;

  embed_kernel<<<NTOK, 256, 0, stream>>>(inp_k, lut, h);
  posemb_kernel<<<2 * S, 384, 0, stream>>>(r2);

  dim3 gProj(D / 64, NTOK / 64);    // 12 x 16
  dim3 gFF1(DI / 64, NTOK / 64);    // 48 x 16
  dim3 gAttn(S, B, H);

  for (int l = 0; l < NL; ++l) {
    const float* wq = Wq + (size_t)l * D * D;
    const float* wk = Wk + (size_t)l * D * D;
    const float* wv = Wv + (size_t)l * D * D;
    const float* wr = Wr + (size_t)l * D * D;
    const float* wo = Wo + (size_t)l * D * D;

    gemm_f32<false, 0><<<gProj, 256, 0, stream>>>(h,  wq, nullptr, q,  NTOK, D, D);
    gemm_f32<false, 0><<<gProj, 256, 0, stream>>>(h,  wk, nullptr, k,  NTOK, D, D);
    gemm_f32<false, 0><<<gProj, 256, 0, stream>>>(h,  wv, nullptr, v,  NTOK, D, D);
    gemm_f32<false, 0><<<gProj, 256, 0, stream>>>(r2, wr, nullptr, kr, NTOK, D, D);

    ef_kernel<<<(NTOK * H * 2 + 255) / 256, 256, 0, stream>>>(
        q, r_s_bias + (size_t)l * D, seg_embed + (size_t)l * 2 * H * DH, ef);

    attn_kernel<<<gAttn, 256, 0, stream>>>(q, k, v, kr, ef, seg_ids, input_mask,
                                           r_w_bias + (size_t)l * D,
                                           r_r_bias + (size_t)l * D, vec);

    gemm_f32<true, 0><<<gProj, 256, 0, stream>>>(vec, wo, nullptr, ao, NTOK, D, D);
    add_ln_kernel<<<NTOK, 256, 0, stream>>>(ao, h, ln_attn_g + (size_t)l * D,
                                            ln_attn_b + (size_t)l * D);

    gemm_f32<false, 1><<<gFF1, 256, 0, stream>>>(h, ff_w1 + (size_t)l * D * DI,
                                                 ff_b1 + (size_t)l * DI, ff1, NTOK, DI, D);
    gemm_f32<false, 0><<<gProj, 256, 0, stream>>>(ff1, ff_w2 + (size_t)l * DI * D,
                                                  ff_b2 + (size_t)l * D, ao, NTOK, D, DI);
    add_ln_kernel<<<NTOK, 256, 0, stream>>>(ao, h, ln_ff_g + (size_t)l * D,
                                            ln_ff_b + (size_t)l * D);
  }
}

// Round 2
// 2908.131 us; speedup vs baseline: 5.2852x; 5.2852x over previous
//
#include <hip/hip_runtime.h>
#include <hip/hip_bf16.h>
#include <math.h>

#define S 512
#define B 2
#define D 768
#define H 12
#define DH 64
#define DI 3072
#define NL 12
#define NTOK (S * B)   // 1024

typedef __attribute__((ext_vector_type(8))) short short8v;
typedef __attribute__((ext_vector_type(4))) float f32x4;

__device__ __forceinline__ unsigned short f2b(float f) {
  union { float f; unsigned int u; } v; v.f = f;
  unsigned int r = v.u + 0x7fffu + ((v.u >> 16) & 1u);
  return (unsigned short)(r >> 16);
}

__device__ __forceinline__ float gelu_f(float x) {
  const float c = 0.7978845608028654f;  // sqrt(2/pi)
  float t = tanhf(c * (x + 0.044715f * x * x * x));
  return x * 0.5f * (1.0f + t);
}

// ---------------- embedding gather ----------------
__global__ __launch_bounds__(256) void embed_kernel(const int* __restrict__ inp_k,
                                                    const float* __restrict__ lut,
                                                    float* __restrict__ h,
                                                    unsigned short* __restrict__ h_bf) {
  int t = blockIdx.x;
  int id = inp_k[t];
  for (int j = threadIdx.x; j < D; j += 256) {
    float v = lut[(size_t)id * D + j];
    h[t * D + j] = v;
    h_bf[t * D + j] = f2b(v);
  }
}

// ---------------- positional embedding -> bf16 [2S, D] ----------------
__global__ __launch_bounds__(384) void posemb_kernel(unsigned short* __restrict__ r2b) {
  int j = blockIdx.x;           // 0..1023
  int d = threadIdx.x;          // 0..383
  float pos = (float)(S - j);
  float inv_freq = expf(-logf(10000.0f) * (2.0f * (float)d / (float)D));
  float x = pos * inv_freq;
  r2b[j * D + d]       = f2b(sinf(x));
  r2b[j * D + 384 + d] = f2b(cosf(x));
}

// ---------------- weight prep: transpose [K][N] f32 -> [N][K] bf16 ------------
__device__ __forceinline__ void transpose64(const float* __restrict__ src,
                                            unsigned short* __restrict__ dst,
                                            int K, int N, int tile, float (*Ls)[65]) {
  int ntk = K >> 6;
  int tk = tile % ntk, tn = tile / ntk;
  int k0 = tk * 64, n0 = tn * 64;
  int tid = threadIdx.x;
  int rr = tid >> 4, c4 = (tid & 15) * 4;
#pragma unroll
  for (int r = 0; r < 4; ++r) {
    int k = rr + r * 16;
    *(float4*)&Ls[k][c4] = *(const float4*)&src[(size_t)(k0 + k) * N + n0 + c4];
  }
  __syncthreads();
#pragma unroll
  for (int r = 0; r < 4; ++r) {
    int nl = rr + r * 16;
    ushort4 o;
    o.x = f2b(Ls[c4 + 0][nl]);
    o.y = f2b(Ls[c4 + 1][nl]);
    o.z = f2b(Ls[c4 + 2][nl]);
    o.w = f2b(Ls[c4 + 3][nl]);
    *(ushort4*)&dst[(size_t)(n0 + nl) * K + k0 + c4] = o;
  }
}

__global__ __launch_bounds__(256) void prep_weights(const float* __restrict__ Wq,
                                                    const float* __restrict__ Wk,
                                                    const float* __restrict__ Wv,
                                                    const float* __restrict__ Wr,
                                                    const float* __restrict__ Wo,
                                                    const float* __restrict__ W1,
                                                    const float* __restrict__ W2,
                                                    unsigned short* __restrict__ wqkv_t,
                                                    unsigned short* __restrict__ wr_t,
                                                    unsigned short* __restrict__ wo_bf,
                                                    unsigned short* __restrict__ w1_t,
                                                    unsigned short* __restrict__ w2_t) {
  __shared__ float Ls[64][65];
  int tb = blockIdx.x;
  if (tb < 432) {
    int which = tb / 144, tile = tb % 144;
    const float* src = which == 0 ? Wq : (which == 1 ? Wk : Wv);
    transpose64(src, wqkv_t + (size_t)which * D * D, D, D, tile, Ls);
  } else if (tb < 576) {
    transpose64(Wr, wr_t, D, D, tb - 432, Ls);
  } else if (tb < 1152) {
    transpose64(W1, w1_t, D, DI, tb - 576, Ls);     // [768][3072] -> [3072][768]
  } else if (tb < 1728) {
    transpose64(W2, w2_t, DI, D, tb - 1152, Ls);    // [3072][768] -> [768][3072]
  } else {
    // Wo already [N_out][K] -> straight cast
    size_t base = (size_t)(tb - 1728) * 2048 + (size_t)threadIdx.x * 8;
    float4 a = *(const float4*)&Wo[base];
    float4 b = *(const float4*)&Wo[base + 4];
    ushort4 o1, o2;
    o1.x = f2b(a.x); o1.y = f2b(a.y); o1.z = f2b(a.z); o1.w = f2b(a.w);
    o2.x = f2b(b.x); o2.y = f2b(b.y); o2.z = f2b(b.z); o2.w = f2b(b.w);
    *(ushort4*)&wo_bf[base] = o1;
    *(ushort4*)&wo_bf[base + 4] = o2;
  }
}

// ---------------- bf16 MFMA GEMM: C[M,N] = A[M,K] @ Wt[N,K]^T (+bias, act) ----
// A bf16 [M][K], Wt bf16 [N][K]. BM=128, BN=NFR*32, BK=64. 4 waves.
template <int NFR, int ACT, int OUTBF>
__global__ __launch_bounds__(256) void gemm_bf16(const unsigned short* __restrict__ A,
                                                 const unsigned short* __restrict__ W,
                                                 const float* __restrict__ bias,
                                                 float* __restrict__ Cf,
                                                 unsigned short* __restrict__ Cb,
                                                 int N, int K) {
  constexpr int BN = NFR * 32;
  constexpr int LDK = 72;   // 64 + 8 pad (16B) -> row stride 144B, kills 32-way conflicts
  __shared__ unsigned short As[128 * LDK];
  __shared__ unsigned short Bs[BN * LDK];
  int bm = blockIdx.y * 128, bn = blockIdx.x * BN;
  int tid = threadIdx.x, lane = tid & 63, w = tid >> 6;
  int wr = w >> 1, wc = w & 1;
  f32x4 acc[4][NFR];
#pragma unroll
  for (int mi = 0; mi < 4; ++mi)
#pragma unroll
    for (int ni = 0; ni < NFR; ++ni)
      acc[mi][ni] = (f32x4){0.f, 0.f, 0.f, 0.f};

  for (int kt = 0; kt < K; kt += 64) {
    __syncthreads();
#pragma unroll
    for (int c = 0; c < 4; ++c) {
      int idx = tid + c * 256;
      int row = idx >> 3, k8 = (idx & 7) * 8;
      *(short8v*)&As[row * LDK + k8] =
          *(const short8v*)&A[(size_t)(bm + row) * K + kt + k8];
    }
#pragma unroll
    for (int c = 0; c < BN / 32; ++c) {
      int idx = tid + c * 256;
      int row = idx >> 3, k8 = (idx & 7) * 8;
      *(short8v*)&Bs[row * LDK + k8] =
          *(const short8v*)&W[(size_t)(bn + row) * K + kt + k8];
    }
    __syncthreads();
#pragma unroll
    for (int ks = 0; ks < 2; ++ks) {
      int kb = ks * 32 + (lane >> 4) * 8;
      short8v af[4], bf[NFR];
#pragma unroll
      for (int mi = 0; mi < 4; ++mi)
        af[mi] = *(const short8v*)&As[(wr * 64 + mi * 16 + (lane & 15)) * LDK + kb];
#pragma unroll
      for (int ni = 0; ni < NFR; ++ni)
        bf[ni] = *(const short8v*)&Bs[(wc * (NFR * 16) + ni * 16 + (lane & 15)) * LDK + kb];
#pragma unroll
      for (int mi = 0; mi < 4; ++mi)
#pragma unroll
        for (int ni = 0; ni < NFR; ++ni)
          acc[mi][ni] = __builtin_amdgcn_mfma_f32_16x16x32_bf16(af[mi], bf[ni], acc[mi][ni], 0, 0, 0);
    }
  }

  int r0 = (lane >> 4) * 4, cc = lane & 15;
#pragma unroll
  for (int mi = 0; mi < 4; ++mi) {
    int row = bm + wr * 64 + mi * 16 + r0;
#pragma unroll
    for (int ni = 0; ni < NFR; ++ni) {
      int col = bn + wc * (NFR * 16) + ni * 16 + cc;
      float bv = bias ? bias[col] : 0.0f;
#pragma unroll
      for (int r = 0; r < 4; ++r) {
        float v = acc[mi][ni][r] + bv;
        if (ACT == 1) v = gelu_f(v);
        if (OUTBF) Cb[(size_t)(row + r) * N + col] = f2b(v);
        else       Cf[(size_t)(row + r) * N + col] = v;
      }
    }
  }
}

// ---------------- segment-bias ef[t, n, s] -----------------------------------
__global__ __launch_bounds__(256) void ef_kernel(const float* __restrict__ qkv,
                                                 const float* __restrict__ rsb,
                                                 const float* __restrict__ segemb,
                                                 float* __restrict__ ef) {
  int idx = blockIdx.x * 256 + threadIdx.x;
  if (idx >= NTOK * H * 2) return;
  int s = idx & 1;
  int n = (idx >> 1) % H;
  int t = idx / (H * 2);
  float acc = 0.0f;
  const float* qp = qkv + (size_t)t * 2304 + n * DH;
  const float* rp = rsb + n * DH;
  const float* sp = segemb + (s * H + n) * DH;
  for (int d = 0; d < DH; ++d)
    acc = fmaf(qp[d] + rp[d], sp[d], acc);
  ef[idx] = acc;
}

// ---------------- fused attention, 16-row i-tile per block --------------------
__global__ __launch_bounds__(256) void attn_kernel(const float* __restrict__ qkv,
                                                   const float* __restrict__ kr,
                                                   const float* __restrict__ ef,
                                                   const int* __restrict__ seg_ids,
                                                   const int* __restrict__ input_mask,
                                                   const float* __restrict__ rwb,
                                                   const float* __restrict__ rrb,
                                                   unsigned short* __restrict__ vec_bf) {
  int it = blockIdx.x * 16, b = blockIdx.y, n = blockIdx.z;
  int tid = threadIdx.x;
  __shared__ float qw[16][64], qr[16][64];
  __shared__ float sc[16][516];
  __shared__ float rinv[16];

  {
    int i = tid >> 4, d4 = (tid & 15) * 4;
    int t = (it + i) * B + b;
    const float4 qv = *(const float4*)&qkv[(size_t)t * 2304 + n * 64 + d4];
    const float4 wv = *(const float4*)&rwb[n * 64 + d4];
    const float4 rv = *(const float4*)&rrb[n * 64 + d4];
    qw[i][d4 + 0] = qv.x + wv.x; qw[i][d4 + 1] = qv.y + wv.y;
    qw[i][d4 + 2] = qv.z + wv.z; qw[i][d4 + 3] = qv.w + wv.w;
    qr[i][d4 + 0] = qv.x + rv.x; qr[i][d4 + 1] = qv.y + rv.y;
    qr[i][d4 + 2] = qv.z + rv.z; qr[i][d4 + 3] = qv.w + rv.w;
  }
  __syncthreads();

  // Phase A: bd[i][j] = qr_i . kr[S - i + j]; iterate u = S - it - 15 .. S - it + 511
  {
    int u0 = S - it - 15;
    int umax = S - it + 511;
    for (int c = 0; c < 3; ++c) {
      int u = u0 + c * 256 + tid;
      if (u > umax) break;
      float accb[16];
#pragma unroll
      for (int i = 0; i < 16; ++i) accb[i] = 0.0f;
      for (int dc = 0; dc < 64; dc += 4) {
        float4 kv = *(const float4*)&kr[(size_t)u * D + n * 64 + dc];
#pragma unroll
        for (int i = 0; i < 16; ++i) {
          float4 q4 = *(const float4*)&qr[i][dc];
          accb[i] = fmaf(q4.x, kv.x, fmaf(q4.y, kv.y, fmaf(q4.z, kv.z, fmaf(q4.w, kv.w, accb[i]))));
        }
      }
#pragma unroll
      for (int i = 0; i < 16; ++i) {
        int j = u - S + it + i;
        if ((unsigned)j < (unsigned)S) sc[i][j] = accb[i];
      }
    }
  }
  __syncthreads();

  // Phase B: += ac + ef, scale, mask
  for (int c = 0; c < 2; ++c) {
    int j = c * 256 + tid;
    float acca[16];
#pragma unroll
    for (int i = 0; i < 16; ++i) acca[i] = 0.0f;
    for (int dc = 0; dc < 64; dc += 4) {
      float4 kv = *(const float4*)&qkv[(size_t)(j * B + b) * 2304 + 768 + n * 64 + dc];
#pragma unroll
      for (int i = 0; i < 16; ++i) {
        float4 q4 = *(const float4*)&qw[i][dc];
        acca[i] = fmaf(q4.x, kv.x, fmaf(q4.y, kv.y, fmaf(q4.z, kv.z, fmaf(q4.w, kv.w, acca[i]))));
      }
    }
    float maskv = -1e30f * (float)input_mask[j * B + b];
    int segj = seg_ids[j * B + b];
#pragma unroll
    for (int i = 0; i < 16; ++i) {
      int t = (it + i) * B + b;
      float e = ef[((size_t)t * H + n) * 2 + (seg_ids[t] != segj ? 1 : 0)];
      sc[i][j] = (sc[i][j] + acca[i] + e) * 0.125f + maskv;
    }
  }
  __syncthreads();

  // softmax per row (16 threads per row)
  {
    int r = tid >> 4, l16 = tid & 15;
    float mx = -3.4e38f;
    for (int j = l16; j < S; j += 16) mx = fmaxf(mx, sc[r][j]);
#pragma unroll
    for (int m = 1; m < 16; m <<= 1) mx = fmaxf(mx, __shfl_xor(mx, m, 16));
    float sum = 0.0f;
    for (int j = l16; j < S; j += 16) {
      float e = expf(sc[r][j] - mx);
      sc[r][j] = e;
      sum += e;
    }
#pragma unroll
    for (int m = 1; m < 16; m <<= 1) sum += __shfl_xor(sum, m, 16);
    if (l16 == 0) rinv[r] = 1.0f / sum;
  }
  __syncthreads();

  // PV: vec[i][d] = (1/sum) * sum_j p[i][j] v[j][d]
  {
    int i = tid >> 4, d4 = (tid & 15) * 4;
    float ax = 0.f, ay = 0.f, az = 0.f, aw = 0.f;
#pragma unroll 4
    for (int j = 0; j < S; ++j) {
      float p = sc[i][j];
      float4 vv = *(const float4*)&qkv[(size_t)(j * B + b) * 2304 + 1536 + n * 64 + d4];
      ax = fmaf(p, vv.x, ax); ay = fmaf(p, vv.y, ay);
      az = fmaf(p, vv.z, az); aw = fmaf(p, vv.w, aw);
    }
    float inv = rinv[i];
    int t = (it + i) * B + b;
    ushort4 o;
    o.x = f2b(ax * inv); o.y = f2b(ay * inv);
    o.z = f2b(az * inv); o.w = f2b(aw * inv);
    *(ushort4*)&vec_bf[(size_t)t * D + n * 64 + d4] = o;
  }
}

// ---------------- residual add + layernorm (writes f32 h and bf16 h_bf) -------
__global__ __launch_bounds__(256) void add_ln_kernel(const float* __restrict__ x,
                                                     float* __restrict__ h,
                                                     unsigned short* __restrict__ h_bf,
                                                     const float* __restrict__ g,
                                                     const float* __restrict__ bi) {
  int t = blockIdx.x;
  int tid = threadIdx.x;
  __shared__ float red[256];
  float v[3];
  float s = 0.0f;
#pragma unroll
  for (int j = 0; j < 3; ++j) {
    int c = tid + j * 256;
    v[j] = x[(size_t)t * D + c] + h[(size_t)t * D + c];
    s += v[j];
  }
  red[tid] = s;
  __syncthreads();
  for (int st = 128; st > 0; st >>= 1) {
    if (tid < st) red[tid] += red[tid + st];
    __syncthreads();
  }
  float mu = red[0] / (float)D;
  __syncthreads();
  float s2 = 0.0f;
#pragma unroll
  for (int j = 0; j < 3; ++j) {
    float dd = v[j] - mu;
    s2 += dd * dd;
  }
  red[tid] = s2;
  __syncthreads();
  for (int st = 128; st > 0; st >>= 1) {
    if (tid < st) red[tid] += red[tid + st];
    __syncthreads();
  }
  float var = red[0] / (float)D;
  float rstd = rsqrtf(var + 1e-3f);
  __syncthreads();
#pragma unroll
  for (int j = 0; j < 3; ++j) {
    int c = tid + j * 256;
    float o = (v[j] - mu) * rstd * g[c] + bi[c];
    h[(size_t)t * D + c] = o;
    h_bf[(size_t)t * D + c] = f2b(o);
  }
}

extern "C" void kernel_launch(void* const* d_in, const int* in_sizes, int n_in,
                              void* d_out, int out_size, void* d_ws, size_t ws_size,
                              hipStream_t stream) {
  const int*   inp_k      = (const int*)d_in[0];
  const int*   seg_ids    = (const int*)d_in[1];
  const int*   input_mask = (const int*)d_in[2];
  const float* lut        = (const float*)d_in[3];
  const float* Wq         = (const float*)d_in[4];
  const float* Wk         = (const float*)d_in[5];
  const float* Wv         = (const float*)d_in[6];
  const float* Wr         = (const float*)d_in[7];
  const float* Wo         = (const float*)d_in[8];
  const float* r_w_bias   = (const float*)d_in[9];
  const float* r_r_bias   = (const float*)d_in[10];
  const float* r_s_bias   = (const float*)d_in[11];
  const float* seg_embed  = (const float*)d_in[12];
  const float* ln_attn_g  = (const float*)d_in[13];
  const float* ln_attn_b  = (const float*)d_in[14];
  const float* ln_ff_g    = (const float*)d_in[15];
  const float* ln_ff_b    = (const float*)d_in[16];
  const float* ff_w1      = (const float*)d_in[17];
  const float* ff_b1      = (const float*)d_in[18];
  const float* ff_w2      = (const float*)d_in[19];
  const float* ff_b2      = (const float*)d_in[20];

  float* h = (float*)d_out;   // f32 [S,B,D]
  char* wp = (char*)d_ws;
  auto alloc = [&](size_t bytes) -> void* {
    void* p = (void*)wp;
    wp += (bytes + 255) & ~(size_t)255;
    return p;
  };
  const size_t TOKD = (size_t)NTOK * D;
  float* qkv   = (float*)alloc((size_t)NTOK * 2304 * 4);
  float* kr    = (float*)alloc(TOKD * 4);
  float* ao    = (float*)alloc(TOKD * 4);
  float* ef    = (float*)alloc((size_t)NTOK * H * 2 * 4);
  unsigned short* h_bf   = (unsigned short*)alloc(TOKD * 2);
  unsigned short* r2_bf  = (unsigned short*)alloc(TOKD * 2);
  unsigned short* vec_bf = (unsigned short*)alloc(TOKD * 2);
  unsigned short* ff1_bf = (unsigned short*)alloc((size_t)NTOK * DI * 2);
  unsigned short* wqkv_t = (unsigned short*)alloc((size_t)3 * D * D * 2);
  unsigned short* wr_t   = (unsigned short*)alloc((size_t)D * D * 2);
  unsigned short* wo_bf  = (unsigned short*)alloc((size_t)D * D * 2);
  unsigned short* w1_t   = (unsigned short*)alloc((size_t)D * DI * 2);
  unsigned short* w2_t   = (unsigned short*)alloc((size_t)DI * D * 2);

  embed_kernel<<<NTOK, 256, 0, stream>>>(inp_k, lut, h, h_bf);
  posemb_kernel<<<2 * S, 384, 0, stream>>>(r2_bf);

  for (int l = 0; l < NL; ++l) {
    prep_weights<<<2016, 256, 0, stream>>>(
        Wq + (size_t)l * D * D, Wk + (size_t)l * D * D, Wv + (size_t)l * D * D,
        Wr + (size_t)l * D * D, Wo + (size_t)l * D * D,
        ff_w1 + (size_t)l * D * DI, ff_w2 + (size_t)l * DI * D,
        wqkv_t, wr_t, wo_bf, w1_t, w2_t);

    gemm_bf16<4, 0, 0><<<dim3(2304 / 128, NTOK / 128), 256, 0, stream>>>(
        h_bf, wqkv_t, nullptr, qkv, nullptr, 2304, D);
    gemm_bf16<2, 0, 0><<<dim3(D / 64, NTOK / 128), 256, 0, stream>>>(
        r2_bf, wr_t, nullptr, kr, nullptr, D, D);

    ef_kernel<<<(NTOK * H * 2 + 255) / 256, 256, 0, stream>>>(
        qkv, r_s_bias + (size_t)l * D, seg_embed + (size_t)l * 2 * H * DH, ef);

    attn_kernel<<<dim3(S / 16, B, H), 256, 0, stream>>>(
        qkv, kr, ef, seg_ids, input_mask,
        r_w_bias + (size_t)l * D, r_r_bias + (size_t)l * D, vec_bf);

    gemm_bf16<2, 0, 0><<<dim3(D / 64, NTOK / 128), 256, 0, stream>>>(
        vec_bf, wo_bf, nullptr, ao, nullptr, D, D);
    add_ln_kernel<<<NTOK, 256, 0, stream>>>(ao, h, h_bf,
                                            ln_attn_g + (size_t)l * D,
                                            ln_attn_b + (size_t)l * D);

    gemm_bf16<4, 1, 1><<<dim3(DI / 128, NTOK / 128), 256, 0, stream>>>(
        h_bf, w1_t, ff_b1 + (size_t)l * DI, nullptr, ff1_bf, DI, D);
    gemm_bf16<2, 0, 0><<<dim3(D / 64, NTOK / 128), 256, 0, stream>>>(
        ff1_bf, w2_t, ff_b2 + (size_t)l * D, ao, nullptr, D, DI);
    add_ln_kernel<<<NTOK, 256, 0, stream>>>(ao, h, h_bf,
                                            ln_ff_g + (size_t)l * D,
                                            ln_ff_b + (size_t)l * D);
  }
}

// Round 3
// 2073.036 us; speedup vs baseline: 7.4143x; 1.4028x over previous
//
#include <hip/hip_runtime.h>
#include <hip/hip_bf16.h>
#include <math.h>

#define S 512
#define B 2
#define D 768
#define H 12
#define DH 64
#define DI 3072
#define NL 12
#define NTOK (S * B)   // 1024

typedef __attribute__((ext_vector_type(8))) short short8v;
typedef __attribute__((ext_vector_type(4))) float f32x4;

__device__ __forceinline__ unsigned short f2b(float f) {
  union { float f; unsigned int u; } v; v.f = f;
  unsigned int r = v.u + 0x7fffu + ((v.u >> 16) & 1u);
  return (unsigned short)(r >> 16);
}
__device__ __forceinline__ float b2f(unsigned short u) {
  union { unsigned int u; float f; } v; v.u = ((unsigned int)u) << 16;
  return v.f;
}

__device__ __forceinline__ float gelu_f(float x) {
  const float c = 0.7978845608028654f;  // sqrt(2/pi)
  float t = tanhf(c * (x + 0.044715f * x * x * x));
  return x * 0.5f * (1.0f + t);
}

// ---------------- embedding gather ----------------
__global__ __launch_bounds__(256) void embed_kernel(const int* __restrict__ inp_k,
                                                    const float* __restrict__ lut,
                                                    float* __restrict__ h,
                                                    unsigned short* __restrict__ h_bf) {
  int t = blockIdx.x;
  int id = inp_k[t];
  for (int j = threadIdx.x; j < D; j += 256) {
    float v = lut[(size_t)id * D + j];
    h[t * D + j] = v;
    h_bf[t * D + j] = f2b(v);
  }
}

// ---------------- positional embedding -> bf16 [2S, D] ----------------
__global__ __launch_bounds__(384) void posemb_kernel(unsigned short* __restrict__ r2b) {
  int j = blockIdx.x;
  int d = threadIdx.x;
  float pos = (float)(S - j);
  float inv_freq = expf(-logf(10000.0f) * (2.0f * (float)d / (float)D));
  float x = pos * inv_freq;
  r2b[j * D + d]       = f2b(sinf(x));
  r2b[j * D + 384 + d] = f2b(cosf(x));
}

// ---------------- weight prep: transpose [K][N] f32 -> [N][K] bf16 ------------
__device__ __forceinline__ void transpose64(const float* __restrict__ src,
                                            unsigned short* __restrict__ dst,
                                            int K, int N, int tile, float (*Ls)[65]) {
  int ntk = K >> 6;
  int tk = tile % ntk, tn = tile / ntk;
  int k0 = tk * 64, n0 = tn * 64;
  int tid = threadIdx.x;
  int rr = tid >> 4, c4 = (tid & 15) * 4;
#pragma unroll
  for (int r = 0; r < 4; ++r) {
    int k = rr + r * 16;
    *(float4*)&Ls[k][c4] = *(const float4*)&src[(size_t)(k0 + k) * N + n0 + c4];
  }
  __syncthreads();
#pragma unroll
  for (int r = 0; r < 4; ++r) {
    int nl = rr + r * 16;
    ushort4 o;
    o.x = f2b(Ls[c4 + 0][nl]);
    o.y = f2b(Ls[c4 + 1][nl]);
    o.z = f2b(Ls[c4 + 2][nl]);
    o.w = f2b(Ls[c4 + 3][nl]);
    *(ushort4*)&dst[(size_t)(n0 + nl) * K + k0 + c4] = o;
  }
}

__global__ __launch_bounds__(256) void prep_weights(const float* __restrict__ Wq,
                                                    const float* __restrict__ Wk,
                                                    const float* __restrict__ Wv,
                                                    const float* __restrict__ Wr,
                                                    const float* __restrict__ Wo,
                                                    const float* __restrict__ W1,
                                                    const float* __restrict__ W2,
                                                    unsigned short* __restrict__ wqkv_t,
                                                    unsigned short* __restrict__ wr_t,
                                                    unsigned short* __restrict__ wo_bf,
                                                    unsigned short* __restrict__ w1_t,
                                                    unsigned short* __restrict__ w2_t) {
  __shared__ float Ls[64][65];
  int tb = blockIdx.x;
  if (tb < 432) {
    int which = tb / 144, tile = tb % 144;
    const float* src = which == 0 ? Wq : (which == 1 ? Wk : Wv);
    transpose64(src, wqkv_t + (size_t)which * D * D, D, D, tile, Ls);
  } else if (tb < 576) {
    transpose64(Wr, wr_t, D, D, tb - 432, Ls);
  } else if (tb < 1152) {
    transpose64(W1, w1_t, D, DI, tb - 576, Ls);
  } else if (tb < 1728) {
    transpose64(W2, w2_t, DI, D, tb - 1152, Ls);
  } else {
    size_t base = (size_t)(tb - 1728) * 2048 + (size_t)threadIdx.x * 8;
    float4 a = *(const float4*)&Wo[base];
    float4 b = *(const float4*)&Wo[base + 4];
    ushort4 o1, o2;
    o1.x = f2b(a.x); o1.y = f2b(a.y); o1.z = f2b(a.z); o1.w = f2b(a.w);
    o2.x = f2b(b.x); o2.y = f2b(b.y); o2.z = f2b(b.z); o2.w = f2b(b.w);
    *(ushort4*)&wo_bf[base] = o1;
    *(ushort4*)&wo_bf[base + 4] = o2;
  }
}

// ---------------- bf16 MFMA GEMM: C[M,N] = A[M,K] @ Wt[N,K]^T (+bias, act) ----
template <int NFR, int ACT, int OUTBF>
__global__ __launch_bounds__(256) void gemm_bf16(const unsigned short* __restrict__ A,
                                                 const unsigned short* __restrict__ W,
                                                 const float* __restrict__ bias,
                                                 float* __restrict__ Cf,
                                                 unsigned short* __restrict__ Cb,
                                                 int N, int K) {
  constexpr int BN = NFR * 32;
  constexpr int LDK = 72;
  __shared__ unsigned short As[128 * LDK];
  __shared__ unsigned short Bs[BN * LDK];
  int bm = blockIdx.y * 128, bn = blockIdx.x * BN;
  int tid = threadIdx.x, lane = tid & 63, w = tid >> 6;
  int wr = w >> 1, wc = w & 1;
  f32x4 acc[4][NFR];
#pragma unroll
  for (int mi = 0; mi < 4; ++mi)
#pragma unroll
    for (int ni = 0; ni < NFR; ++ni)
      acc[mi][ni] = (f32x4){0.f, 0.f, 0.f, 0.f};

  for (int kt = 0; kt < K; kt += 64) {
    __syncthreads();
#pragma unroll
    for (int c = 0; c < 4; ++c) {
      int idx = tid + c * 256;
      int row = idx >> 3, k8 = (idx & 7) * 8;
      *(short8v*)&As[row * LDK + k8] =
          *(const short8v*)&A[(size_t)(bm + row) * K + kt + k8];
    }
#pragma unroll
    for (int c = 0; c < BN / 32; ++c) {
      int idx = tid + c * 256;
      int row = idx >> 3, k8 = (idx & 7) * 8;
      *(short8v*)&Bs[row * LDK + k8] =
          *(const short8v*)&W[(size_t)(bn + row) * K + kt + k8];
    }
    __syncthreads();
#pragma unroll
    for (int ks = 0; ks < 2; ++ks) {
      int kb = ks * 32 + (lane >> 4) * 8;
      short8v af[4], bf[NFR];
#pragma unroll
      for (int mi = 0; mi < 4; ++mi)
        af[mi] = *(const short8v*)&As[(wr * 64 + mi * 16 + (lane & 15)) * LDK + kb];
#pragma unroll
      for (int ni = 0; ni < NFR; ++ni)
        bf[ni] = *(const short8v*)&Bs[(wc * (NFR * 16) + ni * 16 + (lane & 15)) * LDK + kb];
#pragma unroll
      for (int mi = 0; mi < 4; ++mi)
#pragma unroll
        for (int ni = 0; ni < NFR; ++ni)
          acc[mi][ni] = __builtin_amdgcn_mfma_f32_16x16x32_bf16(af[mi], bf[ni], acc[mi][ni], 0, 0, 0);
    }
  }

  int r0 = (lane >> 4) * 4, cc = lane & 15;
#pragma unroll
  for (int mi = 0; mi < 4; ++mi) {
    int row = bm + wr * 64 + mi * 16 + r0;
#pragma unroll
    for (int ni = 0; ni < NFR; ++ni) {
      int col = bn + wc * (NFR * 16) + ni * 16 + cc;
      float bv = bias ? bias[col] : 0.0f;
#pragma unroll
      for (int r = 0; r < 4; ++r) {
        float v = acc[mi][ni][r] + bv;
        if (ACT == 1) v = gelu_f(v);
        if (OUTBF) Cb[(size_t)(row + r) * N + col] = f2b(v);
        else       Cf[(size_t)(row + r) * N + col] = v;
      }
    }
  }
}

// ---------------- MFMA fused attention ----------------------------------------
// Block: (i-tile of 64 rows, b, n). 4 waves.
// Phase 1: per 64-col j-tile: ac + bd (128-wide kr window, rel-shift col=64-il+jl)
//          + ef + mask -> f32 logits to global scratch sc[64][512].
// Phase 2: row max. Phase 3: per j-tile exp->bf16 probs in LDS + V^T in LDS -> PV MFMA.
__global__ __launch_bounds__(256) void attn_kernel(const unsigned short* __restrict__ qkv,
                                                   const unsigned short* __restrict__ krb,
                                                   const int* __restrict__ seg_ids,
                                                   const int* __restrict__ input_mask,
                                                   const float* __restrict__ rwb,
                                                   const float* __restrict__ rrb,
                                                   const float* __restrict__ rsb,
                                                   const float* __restrict__ segemb,
                                                   float* __restrict__ scg,
                                                   unsigned short* __restrict__ vec_bf) {
  __shared__ __align__(16) char smem[64512];
  unsigned short* qw_s = (unsigned short*)(smem + 0);      // [64][72]
  unsigned short* qr_s = (unsigned short*)(smem + 9216);   // [64][72]
  unsigned short* k_s  = (unsigned short*)(smem + 18432);  // [64][72]
  unsigned short* kr_s = (unsigned short*)(smem + 27648);  // [128][72]
  unsigned short* bd_s = (unsigned short*)(smem + 46080);  // [64][136]
  float* efs    = (float*)(smem + 63488);                  // [2][64]
  float* rinv_s = (float*)(smem + 64000);                  // [64]
  int*   segrow = (int*)(smem + 64256);                    // [64]
  unsigned short* pb_s = (unsigned short*)(smem + 0);      // [64][72] (aliases qw_s)
  unsigned short* vt_s = (unsigned short*)(smem + 9216);   // [64][72] (aliases qr_s)

  const int it = blockIdx.x * 64, b = blockIdx.y, n = blockIdx.z;
  const int tid = threadIdx.x, lane = tid & 63, w = tid >> 6;
  float* sc = scg + (size_t)((blockIdx.z * 2 + blockIdx.y) * 8 + blockIdx.x) * (64 * 512);

  // ---- stage qw/qr (q + biases), ef table, segrow
  {
    int il = tid >> 2, d16 = (tid & 3) * 16;
    int t = (it + il) * B + b;
    short8v q0 = *(const short8v*)&qkv[(size_t)t * 2304 + n * 64 + d16];
    short8v q1 = *(const short8v*)&qkv[(size_t)t * 2304 + n * 64 + d16 + 8];
    short8v ow0, ow1, or0, or1;
#pragma unroll
    for (int e = 0; e < 8; ++e) {
      float f0 = b2f((unsigned short)q0[e]);
      float f1 = b2f((unsigned short)q1[e]);
      ow0[e] = (short)f2b(f0 + rwb[n * 64 + d16 + e]);
      ow1[e] = (short)f2b(f1 + rwb[n * 64 + d16 + 8 + e]);
      or0[e] = (short)f2b(f0 + rrb[n * 64 + d16 + e]);
      or1[e] = (short)f2b(f1 + rrb[n * 64 + d16 + 8 + e]);
    }
    *(short8v*)&qw_s[il * 72 + d16] = ow0;
    *(short8v*)&qw_s[il * 72 + d16 + 8] = ow1;
    *(short8v*)&qr_s[il * 72 + d16] = or0;
    *(short8v*)&qr_s[il * 72 + d16 + 8] = or1;
  }
  if (tid < 128) {
    int il = tid >> 1, s = tid & 1;
    int t = (it + il) * B + b;
    float acc = 0.0f;
    for (int d = 0; d < 64; ++d)
      acc = fmaf(b2f(qkv[(size_t)t * 2304 + n * 64 + d]) + rsb[n * 64 + d],
                 segemb[(s * H + n) * 64 + d], acc);
    efs[s * 64 + il] = acc;
  }
  if (tid < 64) segrow[tid] = seg_ids[(it + tid) * B + b];

  // ---- Phase 1: logits
  for (int jt = 0; jt < 512; jt += 64) {
    __syncthreads();
    {
#pragma unroll
      for (int c = 0; c < 2; ++c) {
        int idx = tid + c * 256;
        int row = idx >> 3, k8 = (idx & 7) * 8;
        *(short8v*)&k_s[row * 72 + k8] =
            *(const short8v*)&qkv[(size_t)((jt + row) * B + b) * 2304 + 768 + n * 64 + k8];
      }
      int u0 = 448 - it + jt;
#pragma unroll
      for (int c = 0; c < 4; ++c) {
        int idx = tid + c * 256;
        int row = idx >> 3, k8 = (idx & 7) * 8;
        *(short8v*)&kr_s[row * 72 + k8] =
            *(const short8v*)&krb[(size_t)(u0 + row) * 768 + n * 64 + k8];
      }
    }
    __syncthreads();

    f32x4 aac[4], abd[4][2];
#pragma unroll
    for (int mi = 0; mi < 4; ++mi) {
      aac[mi] = (f32x4){0.f, 0.f, 0.f, 0.f};
      abd[mi][0] = (f32x4){0.f, 0.f, 0.f, 0.f};
      abd[mi][1] = (f32x4){0.f, 0.f, 0.f, 0.f};
    }
#pragma unroll
    for (int ks = 0; ks < 2; ++ks) {
      int kb = ks * 32 + (lane >> 4) * 8;
      short8v aw[4], ar[4];
#pragma unroll
      for (int mi = 0; mi < 4; ++mi) {
        aw[mi] = *(const short8v*)&qw_s[(mi * 16 + (lane & 15)) * 72 + kb];
        ar[mi] = *(const short8v*)&qr_s[(mi * 16 + (lane & 15)) * 72 + kb];
      }
      short8v bk  = *(const short8v*)&k_s[(w * 16 + (lane & 15)) * 72 + kb];
      short8v br0 = *(const short8v*)&kr_s[(w * 32 + (lane & 15)) * 72 + kb];
      short8v br1 = *(const short8v*)&kr_s[(w * 32 + 16 + (lane & 15)) * 72 + kb];
#pragma unroll
      for (int mi = 0; mi < 4; ++mi) {
        aac[mi] = __builtin_amdgcn_mfma_f32_16x16x32_bf16(aw[mi], bk, aac[mi], 0, 0, 0);
        abd[mi][0] = __builtin_amdgcn_mfma_f32_16x16x32_bf16(ar[mi], br0, abd[mi][0], 0, 0, 0);
        abd[mi][1] = __builtin_amdgcn_mfma_f32_16x16x32_bf16(ar[mi], br1, abd[mi][1], 0, 0, 0);
      }
    }
    // write bd window to LDS (bf16) for the rel-shift
#pragma unroll
    for (int mi = 0; mi < 4; ++mi)
#pragma unroll
      for (int ni = 0; ni < 2; ++ni)
#pragma unroll
        for (int r = 0; r < 4; ++r)
          bd_s[(mi * 16 + (lane >> 4) * 4 + r) * 136 + w * 32 + ni * 16 + (lane & 15)] =
              f2b(abd[mi][ni][r]);
    __syncthreads();

    // combine: sc = (ac + bd[shift] + ef)*scale + mask
    {
      int jl = w * 16 + (lane & 15);
      int jg = jt + jl;
      float maskterm = -1e30f * (float)input_mask[jg * B + b];
      int segj = seg_ids[jg * B + b];
#pragma unroll
      for (int mi = 0; mi < 4; ++mi)
#pragma unroll
        for (int r = 0; r < 4; ++r) {
          int il = mi * 16 + (lane >> 4) * 4 + r;
          float bd = b2f(bd_s[il * 136 + 64 - il + jl]);
          float e = efs[(segrow[il] != segj ? 1 : 0) * 64 + il];
          sc[il * 512 + jg] = (aac[mi][r] + bd + e) * 0.125f + maskterm;
        }
    }
  }
  __syncthreads();

  // ---- Phase 2: row max (4 lanes per row)
  int srow = tid >> 2;
  float mx = -3.4e38f;
  {
    int c0 = (tid & 3) * 128;
    for (int c = 0; c < 128; c += 4) {
      float4 vv = *(const float4*)&sc[srow * 512 + c0 + c];
      mx = fmaxf(mx, fmaxf(fmaxf(vv.x, vv.y), fmaxf(vv.z, vv.w)));
    }
    mx = fmaxf(mx, __shfl_xor(mx, 1, 4));
    mx = fmaxf(mx, __shfl_xor(mx, 2, 4));
  }

  // ---- Phase 3: PV with on-the-fly exp
  f32x4 acc_v[4];
#pragma unroll
  for (int mi = 0; mi < 4; ++mi) acc_v[mi] = (f32x4){0.f, 0.f, 0.f, 0.f};
  float rsum = 0.0f;
  const int vkey = (w & 1) * 8;   // vt_s column swizzle key for this wave's d range

  for (int jt = 0; jt < 512; jt += 64) {
    __syncthreads();
    // fill probs tile (unnormalized exp, bf16)
    {
      int c16 = (tid & 3) * 16;
#pragma unroll
      for (int half = 0; half < 2; ++half) {
        float4 fa = *(const float4*)&sc[srow * 512 + jt + c16 + half * 8];
        float4 fb = *(const float4*)&sc[srow * 512 + jt + c16 + half * 8 + 4];
        float e0 = __expf(fa.x - mx), e1 = __expf(fa.y - mx);
        float e2 = __expf(fa.z - mx), e3 = __expf(fa.w - mx);
        float e4 = __expf(fb.x - mx), e5 = __expf(fb.y - mx);
        float e6 = __expf(fb.z - mx), e7 = __expf(fb.w - mx);
        rsum += e0 + e1 + e2 + e3 + e4 + e5 + e6 + e7;
        short8v o;
        o[0] = (short)f2b(e0); o[1] = (short)f2b(e1);
        o[2] = (short)f2b(e2); o[3] = (short)f2b(e3);
        o[4] = (short)f2b(e4); o[5] = (short)f2b(e5);
        o[6] = (short)f2b(e6); o[7] = (short)f2b(e7);
        *(short8v*)&pb_s[srow * 72 + c16 + half * 8] = o;
      }
    }
    // fill V^T tile (bank-swizzled on d bit 4)
    {
      int vj = tid >> 2, vd16 = (tid & 3) * 16;
      int key = (vd16 & 16) ? 8 : 0;
      short8v v0 = *(const short8v*)&qkv[(size_t)((jt + vj) * B + b) * 2304 + 1536 + n * 64 + vd16];
      short8v v1 = *(const short8v*)&qkv[(size_t)((jt + vj) * B + b) * 2304 + 1536 + n * 64 + vd16 + 8];
#pragma unroll
      for (int e = 0; e < 8; ++e) {
        vt_s[(vd16 + e) * 72 + (vj ^ key)] = (unsigned short)v0[e];
        vt_s[(vd16 + 8 + e) * 72 + (vj ^ key)] = (unsigned short)v1[e];
      }
    }
    __syncthreads();
#pragma unroll
    for (int ks = 0; ks < 2; ++ks) {
      int kb = ks * 32 + (lane >> 4) * 8;
      short8v bv = *(const short8v*)&vt_s[(w * 16 + (lane & 15)) * 72 + (kb ^ vkey)];
#pragma unroll
      for (int mi = 0; mi < 4; ++mi) {
        short8v ap = *(const short8v*)&pb_s[(mi * 16 + (lane & 15)) * 72 + kb];
        acc_v[mi] = __builtin_amdgcn_mfma_f32_16x16x32_bf16(ap, bv, acc_v[mi], 0, 0, 0);
      }
    }
  }
  // row sums -> rinv
  rsum += __shfl_xor(rsum, 1, 4);
  rsum += __shfl_xor(rsum, 2, 4);
  if ((tid & 3) == 0) rinv_s[srow] = 1.0f / rsum;
  __syncthreads();

  // epilogue
#pragma unroll
  for (int mi = 0; mi < 4; ++mi)
#pragma unroll
    for (int r = 0; r < 4; ++r) {
      int row = mi * 16 + (lane >> 4) * 4 + r;
      int d = w * 16 + (lane & 15);
      int t = (it + row) * B + b;
      vec_bf[(size_t)t * D + n * 64 + d] = f2b(acc_v[mi][r] * rinv_s[row]);
    }
}

// ---------------- residual add + layernorm (writes f32 h and bf16 h_bf) -------
__global__ __launch_bounds__(256) void add_ln_kernel(const float* __restrict__ x,
                                                     float* __restrict__ h,
                                                     unsigned short* __restrict__ h_bf,
                                                     const float* __restrict__ g,
                                                     const float* __restrict__ bi) {
  int t = blockIdx.x;
  int tid = threadIdx.x;
  __shared__ float red[256];
  float v[3];
  float s = 0.0f;
#pragma unroll
  for (int j = 0; j < 3; ++j) {
    int c = tid + j * 256;
    v[j] = x[(size_t)t * D + c] + h[(size_t)t * D + c];
    s += v[j];
  }
  red[tid] = s;
  __syncthreads();
  for (int st = 128; st > 0; st >>= 1) {
    if (tid < st) red[tid] += red[tid + st];
    __syncthreads();
  }
  float mu = red[0] / (float)D;
  __syncthreads();
  float s2 = 0.0f;
#pragma unroll
  for (int j = 0; j < 3; ++j) {
    float dd = v[j] - mu;
    s2 += dd * dd;
  }
  red[tid] = s2;
  __syncthreads();
  for (int st = 128; st > 0; st >>= 1) {
    if (tid < st) red[tid] += red[tid + st];
    __syncthreads();
  }
  float var = red[0] / (float)D;
  float rstd = rsqrtf(var + 1e-3f);
  __syncthreads();
#pragma unroll
  for (int j = 0; j < 3; ++j) {
    int c = tid + j * 256;
    float o = (v[j] - mu) * rstd * g[c] + bi[c];
    h[(size_t)t * D + c] = o;
    h_bf[(size_t)t * D + c] = f2b(o);
  }
}

extern "C" void kernel_launch(void* const* d_in, const int* in_sizes, int n_in,
                              void* d_out, int out_size, void* d_ws, size_t ws_size,
                              hipStream_t stream) {
  const int*   inp_k      = (const int*)d_in[0];
  const int*   seg_ids    = (const int*)d_in[1];
  const int*   input_mask = (const int*)d_in[2];
  const float* lut        = (const float*)d_in[3];
  const float* Wq         = (const float*)d_in[4];
  const float* Wk         = (const float*)d_in[5];
  const float* Wv         = (const float*)d_in[6];
  const float* Wr         = (const float*)d_in[7];
  const float* Wo         = (const float*)d_in[8];
  const float* r_w_bias   = (const float*)d_in[9];
  const float* r_r_bias   = (const float*)d_in[10];
  const float* r_s_bias   = (const float*)d_in[11];
  const float* seg_embed  = (const float*)d_in[12];
  const float* ln_attn_g  = (const float*)d_in[13];
  const float* ln_attn_b  = (const float*)d_in[14];
  const float* ln_ff_g    = (const float*)d_in[15];
  const float* ln_ff_b    = (const float*)d_in[16];
  const float* ff_w1      = (const float*)d_in[17];
  const float* ff_b1      = (const float*)d_in[18];
  const float* ff_w2      = (const float*)d_in[19];
  const float* ff_b2      = (const float*)d_in[20];

  float* h = (float*)d_out;
  char* wp = (char*)d_ws;
  auto alloc = [&](size_t bytes) -> void* {
    void* p = (void*)wp;
    wp += (bytes + 255) & ~(size_t)255;
    return p;
  };
  const size_t TOKD = (size_t)NTOK * D;
  unsigned short* qkv_bf = (unsigned short*)alloc((size_t)NTOK * 2304 * 2);
  unsigned short* kr_bf  = (unsigned short*)alloc(TOKD * 2);
  float* ao = (float*)alloc(TOKD * 4);
  float* scg = (float*)alloc((size_t)192 * 64 * 512 * 4);
  unsigned short* h_bf   = (unsigned short*)alloc(TOKD * 2);
  unsigned short* r2_bf  = (unsigned short*)alloc(TOKD * 2);
  unsigned short* vec_bf = (unsigned short*)alloc(TOKD * 2);
  unsigned short* ff1_bf = (unsigned short*)alloc((size_t)NTOK * DI * 2);
  unsigned short* wqkv_t = (unsigned short*)alloc((size_t)3 * D * D * 2);
  unsigned short* wr_t   = (unsigned short*)alloc((size_t)D * D * 2);
  unsigned short* wo_bf  = (unsigned short*)alloc((size_t)D * D * 2);
  unsigned short* w1_t   = (unsigned short*)alloc((size_t)D * DI * 2);
  unsigned short* w2_t   = (unsigned short*)alloc((size_t)DI * D * 2);

  embed_kernel<<<NTOK, 256, 0, stream>>>(inp_k, lut, h, h_bf);
  posemb_kernel<<<2 * S, 384, 0, stream>>>(r2_bf);

  for (int l = 0; l < NL; ++l) {
    prep_weights<<<2016, 256, 0, stream>>>(
        Wq + (size_t)l * D * D, Wk + (size_t)l * D * D, Wv + (size_t)l * D * D,
        Wr + (size_t)l * D * D, Wo + (size_t)l * D * D,
        ff_w1 + (size_t)l * D * DI, ff_w2 + (size_t)l * DI * D,
        wqkv_t, wr_t, wo_bf, w1_t, w2_t);

    gemm_bf16<4, 0, 1><<<dim3(2304 / 128, NTOK / 128), 256, 0, stream>>>(
        h_bf, wqkv_t, nullptr, nullptr, qkv_bf, 2304, D);
    gemm_bf16<2, 0, 1><<<dim3(D / 64, NTOK / 128), 256, 0, stream>>>(
        r2_bf, wr_t, nullptr, nullptr, kr_bf, D, D);

    attn_kernel<<<dim3(8, B, H), 256, 0, stream>>>(
        qkv_bf, kr_bf, seg_ids, input_mask,
        r_w_bias + (size_t)l * D, r_r_bias + (size_t)l * D,
        r_s_bias + (size_t)l * D, seg_embed + (size_t)l * 2 * H * DH,
        scg, vec_bf);

    gemm_bf16<2, 0, 0><<<dim3(D / 64, NTOK / 128), 256, 0, stream>>>(
        vec_bf, wo_bf, nullptr, ao, nullptr, D, D);
    add_ln_kernel<<<NTOK, 256, 0, stream>>>(ao, h, h_bf,
                                            ln_attn_g + (size_t)l * D,
                                            ln_attn_b + (size_t)l * D);

    gemm_bf16<4, 1, 1><<<dim3(DI / 128, NTOK / 128), 256, 0, stream>>>(
        h_bf, w1_t, ff_b1 + (size_t)l * DI, nullptr, ff1_bf, DI, D);
    gemm_bf16<2, 0, 0><<<dim3(D / 64, NTOK / 128), 256, 0, stream>>>(
        ff1_bf, w2_t, ff_b2 + (size_t)l * D, ao, nullptr, D, DI);
    add_ln_kernel<<<NTOK, 256, 0, stream>>>(ao, h, h_bf,
                                            ln_ff_g + (size_t)l * D,
                                            ln_ff_b + (size_t)l * D);
  }
}

// Round 4
// 1640.313 us; speedup vs baseline: 9.3702x; 1.2638x over previous
//
#include <hip/hip_runtime.h>
#include <hip/hip_bf16.h>
#include <math.h>

#define S 512
#define B 2
#define D 768
#define H 12
#define DH 64
#define DI 3072
#define NL 12
#define NTOK (S * B)   // 1024

typedef __attribute__((ext_vector_type(8))) short short8v;
typedef __attribute__((ext_vector_type(4))) float f32x4;

__device__ __forceinline__ unsigned short f2b(float f) {
  union { float f; unsigned int u; } v; v.f = f;
  unsigned int r = v.u + 0x7fffu + ((v.u >> 16) & 1u);
  return (unsigned short)(r >> 16);
}
__device__ __forceinline__ float b2f(unsigned short u) {
  union { unsigned int u; float f; } v; v.u = ((unsigned int)u) << 16;
  return v.f;
}

__device__ __forceinline__ float gelu_f(float x) {
  const float c = 0.7978845608028654f;  // sqrt(2/pi)
  float t = tanhf(c * (x + 0.044715f * x * x * x));
  return x * 0.5f * (1.0f + t);
}

// ---------------- embedding gather ----------------
__global__ __launch_bounds__(256) void embed_kernel(const int* __restrict__ inp_k,
                                                    const float* __restrict__ lut,
                                                    float* __restrict__ h,
                                                    unsigned short* __restrict__ h_bf) {
  int t = blockIdx.x;
  int id = inp_k[t];
  for (int j = threadIdx.x; j < D; j += 256) {
    float v = lut[(size_t)id * D + j];
    h[t * D + j] = v;
    h_bf[t * D + j] = f2b(v);
  }
}

// ---------------- positional embedding -> bf16 [2S, D] ----------------
__global__ __launch_bounds__(384) void posemb_kernel(unsigned short* __restrict__ r2b) {
  int j = blockIdx.x;
  int d = threadIdx.x;
  float pos = (float)(S - j);
  float inv_freq = expf(-logf(10000.0f) * (2.0f * (float)d / (float)D));
  float x = pos * inv_freq;
  r2b[j * D + d]       = f2b(sinf(x));
  r2b[j * D + 384 + d] = f2b(cosf(x));
}

// ---------------- weight prep: transpose [K][N] f32 -> [N][K] bf16 ------------
__device__ __forceinline__ void transpose64(const float* __restrict__ src,
                                            unsigned short* __restrict__ dst,
                                            int K, int N, int tile, float (*Ls)[65]) {
  int ntk = K >> 6;
  int tk = tile % ntk, tn = tile / ntk;
  int k0 = tk * 64, n0 = tn * 64;
  int tid = threadIdx.x;
  int rr = tid >> 4, c4 = (tid & 15) * 4;
#pragma unroll
  for (int r = 0; r < 4; ++r) {
    int k = rr + r * 16;
    *(float4*)&Ls[k][c4] = *(const float4*)&src[(size_t)(k0 + k) * N + n0 + c4];
  }
  __syncthreads();
#pragma unroll
  for (int r = 0; r < 4; ++r) {
    int nl = rr + r * 16;
    ushort4 o;
    o.x = f2b(Ls[c4 + 0][nl]);
    o.y = f2b(Ls[c4 + 1][nl]);
    o.z = f2b(Ls[c4 + 2][nl]);
    o.w = f2b(Ls[c4 + 3][nl]);
    *(ushort4*)&dst[(size_t)(n0 + nl) * K + k0 + c4] = o;
  }
}

// all 12 layers in one dispatch: grid = 12 * 2016
__global__ __launch_bounds__(256) void prep_all(const float* __restrict__ Wq,
                                                const float* __restrict__ Wk,
                                                const float* __restrict__ Wv,
                                                const float* __restrict__ Wr,
                                                const float* __restrict__ Wo,
                                                const float* __restrict__ W1,
                                                const float* __restrict__ W2,
                                                unsigned short* __restrict__ wqkv_t,
                                                unsigned short* __restrict__ wr_t,
                                                unsigned short* __restrict__ wo_bf,
                                                unsigned short* __restrict__ w1_t,
                                                unsigned short* __restrict__ w2_t) {
  __shared__ float Ls[64][65];
  const size_t DD = (size_t)D * D;
  const size_t DDI = (size_t)D * DI;
  int tb = blockIdx.x;
  int l = tb / 2016, t2 = tb % 2016;
  if (t2 < 432) {
    int which = t2 / 144, tile = t2 % 144;
    const float* src = (which == 0 ? Wq : (which == 1 ? Wk : Wv)) + l * DD;
    transpose64(src, wqkv_t + l * 3 * DD + which * DD, D, D, tile, Ls);
  } else if (t2 < 576) {
    transpose64(Wr + l * DD, wr_t + l * DD, D, D, t2 - 432, Ls);
  } else if (t2 < 1152) {
    transpose64(W1 + l * DDI, w1_t + l * DDI, D, DI, t2 - 576, Ls);
  } else if (t2 < 1728) {
    transpose64(W2 + l * DDI, w2_t + l * DDI, DI, D, t2 - 1152, Ls);
  } else {
    size_t base = l * DD + (size_t)(t2 - 1728) * 2048 + (size_t)threadIdx.x * 8;
    float4 a = *(const float4*)&Wo[base];
    float4 b = *(const float4*)&Wo[base + 4];
    ushort4 o1, o2;
    o1.x = f2b(a.x); o1.y = f2b(a.y); o1.z = f2b(a.z); o1.w = f2b(a.w);
    o2.x = f2b(b.x); o2.y = f2b(b.y); o2.z = f2b(b.z); o2.w = f2b(b.w);
    *(ushort4*)&wo_bf[base] = o1;
    *(ushort4*)&wo_bf[base + 4] = o2;
  }
}

// ---------------- shared MFMA GEMM tile body: BM=128, BN=128, 4 waves ---------
// A bf16 [M][K] (row stride K), W bf16 [N][K]. C = A @ W^T over K-range [kbeg,kend).
template <int ACT, int OUTBF>
__device__ __forceinline__ void gemm_tile(const unsigned short* __restrict__ A,
                                          const unsigned short* __restrict__ W,
                                          const float* __restrict__ bias,
                                          float* __restrict__ Cf,
                                          unsigned short* __restrict__ Cb,
                                          int N, int K, int bm, int bn,
                                          int kbeg, int kend) {
  constexpr int LDK = 72;
  __shared__ unsigned short As[128 * LDK];
  __shared__ unsigned short Bs[128 * LDK];
  int tid = threadIdx.x, lane = tid & 63, w = tid >> 6;
  int wr = w >> 1, wc = w & 1;
  f32x4 acc[4][4];
#pragma unroll
  for (int mi = 0; mi < 4; ++mi)
#pragma unroll
    for (int ni = 0; ni < 4; ++ni)
      acc[mi][ni] = (f32x4){0.f, 0.f, 0.f, 0.f};

  for (int kt = kbeg; kt < kend; kt += 64) {
    __syncthreads();
#pragma unroll
    for (int c = 0; c < 4; ++c) {
      int idx = tid + c * 256;
      int row = idx >> 3, k8 = (idx & 7) * 8;
      *(short8v*)&As[row * LDK + k8] =
          *(const short8v*)&A[(size_t)(bm + row) * K + kt + k8];
    }
#pragma unroll
    for (int c = 0; c < 4; ++c) {
      int idx = tid + c * 256;
      int row = idx >> 3, k8 = (idx & 7) * 8;
      *(short8v*)&Bs[row * LDK + k8] =
          *(const short8v*)&W[(size_t)(bn + row) * K + kt + k8];
    }
    __syncthreads();
#pragma unroll
    for (int ks = 0; ks < 2; ++ks) {
      int kb = ks * 32 + (lane >> 4) * 8;
      short8v af[4], bf[4];
#pragma unroll
      for (int mi = 0; mi < 4; ++mi)
        af[mi] = *(const short8v*)&As[(wr * 64 + mi * 16 + (lane & 15)) * LDK + kb];
#pragma unroll
      for (int ni = 0; ni < 4; ++ni)
        bf[ni] = *(const short8v*)&Bs[(wc * 64 + ni * 16 + (lane & 15)) * LDK + kb];
#pragma unroll
      for (int mi = 0; mi < 4; ++mi)
#pragma unroll
        for (int ni = 0; ni < 4; ++ni)
          acc[mi][ni] = __builtin_amdgcn_mfma_f32_16x16x32_bf16(af[mi], bf[ni], acc[mi][ni], 0, 0, 0);
    }
  }

  int r0 = (lane >> 4) * 4, cc = lane & 15;
#pragma unroll
  for (int mi = 0; mi < 4; ++mi) {
    int row = bm + wr * 64 + mi * 16 + r0;
#pragma unroll
    for (int ni = 0; ni < 4; ++ni) {
      int col = bn + wc * 64 + ni * 16 + cc;
      float bv = bias ? bias[col] : 0.0f;
#pragma unroll
      for (int r = 0; r < 4; ++r) {
        float v = acc[mi][ni][r] + bv;
        if (ACT == 1) v = gelu_f(v);
        if (OUTBF) Cb[(size_t)(row + r) * N + col] = f2b(v);
        else       Cf[(size_t)(row + r) * N + col] = v;
      }
    }
  }
}

// merged qkv + kr projection: grid.x = 144 + 48 = 192
__global__ __launch_bounds__(256) void gemm_qkvkr(const unsigned short* __restrict__ h_bf,
                                                  const unsigned short* __restrict__ wqkv,
                                                  const unsigned short* __restrict__ r2_bf,
                                                  const unsigned short* __restrict__ wr,
                                                  unsigned short* __restrict__ qkv_bf,
                                                  unsigned short* __restrict__ kr_bf) {
  int bx = blockIdx.x;
  const unsigned short *A, *W;
  unsigned short* C;
  int N, bm, bn;
  if (bx < 144) {
    A = h_bf; W = wqkv; C = qkv_bf; N = 2304;
    bm = (bx / 18) * 128; bn = (bx % 18) * 128;
  } else {
    int b2 = bx - 144;
    A = r2_bf; W = wr; C = kr_bf; N = 768;
    bm = (b2 / 6) * 128; bn = (b2 % 6) * 128;
  }
  gemm_tile<0, 1>(A, W, nullptr, nullptr, C, N, 768, bm, bn, 0, 768);
}

// plain bf16-out GEMM with bias/act: grid.x = ncb * (M/128)
template <int ACT>
__global__ __launch_bounds__(256) void gemm_bias(const unsigned short* __restrict__ A,
                                                 const unsigned short* __restrict__ W,
                                                 const float* __restrict__ bias,
                                                 unsigned short* __restrict__ C,
                                                 int N, int K, int ncb) {
  int bx = blockIdx.x;
  gemm_tile<ACT, 1>(A, W, bias, nullptr, C, N, K, (bx / ncb) * 128, (bx % ncb) * 128, 0, K);
}

// split-K GEMM -> f32 partials. grid = (N/128, M/128, KS), kch = K/KS
__global__ __launch_bounds__(256) void gemm_splitk(const unsigned short* __restrict__ A,
                                                   const unsigned short* __restrict__ W,
                                                   float* __restrict__ part,
                                                   int N, int K, int kch) {
  int kz = blockIdx.z;
  float* Cf = part + (size_t)kz * NTOK * N;
  gemm_tile<0, 0>(A, W, nullptr, Cf, nullptr, N, K,
                  blockIdx.y * 128, blockIdx.x * 128, kz * kch, (kz + 1) * kch);
}

// ---------------- MFMA fused attention (unchanged from round 2) ---------------
__global__ __launch_bounds__(256) void attn_kernel(const unsigned short* __restrict__ qkv,
                                                   const unsigned short* __restrict__ krb,
                                                   const int* __restrict__ seg_ids,
                                                   const int* __restrict__ input_mask,
                                                   const float* __restrict__ rwb,
                                                   const float* __restrict__ rrb,
                                                   const float* __restrict__ rsb,
                                                   const float* __restrict__ segemb,
                                                   float* __restrict__ scg,
                                                   unsigned short* __restrict__ vec_bf) {
  __shared__ __align__(16) char smem[64512];
  unsigned short* qw_s = (unsigned short*)(smem + 0);      // [64][72]
  unsigned short* qr_s = (unsigned short*)(smem + 9216);   // [64][72]
  unsigned short* k_s  = (unsigned short*)(smem + 18432);  // [64][72]
  unsigned short* kr_s = (unsigned short*)(smem + 27648);  // [128][72]
  unsigned short* bd_s = (unsigned short*)(smem + 46080);  // [64][136]
  float* efs    = (float*)(smem + 63488);                  // [2][64]
  float* rinv_s = (float*)(smem + 64000);                  // [64]
  int*   segrow = (int*)(smem + 64256);                    // [64]
  unsigned short* pb_s = (unsigned short*)(smem + 0);      // [64][72] (aliases qw_s)
  unsigned short* vt_s = (unsigned short*)(smem + 9216);   // [64][72] (aliases qr_s)

  const int it = blockIdx.x * 64, b = blockIdx.y, n = blockIdx.z;
  const int tid = threadIdx.x, lane = tid & 63, w = tid >> 6;
  float* sc = scg + (size_t)((blockIdx.z * 2 + blockIdx.y) * 8 + blockIdx.x) * (64 * 512);

  {
    int il = tid >> 2, d16 = (tid & 3) * 16;
    int t = (it + il) * B + b;
    short8v q0 = *(const short8v*)&qkv[(size_t)t * 2304 + n * 64 + d16];
    short8v q1 = *(const short8v*)&qkv[(size_t)t * 2304 + n * 64 + d16 + 8];
    short8v ow0, ow1, or0, or1;
#pragma unroll
    for (int e = 0; e < 8; ++e) {
      float f0 = b2f((unsigned short)q0[e]);
      float f1 = b2f((unsigned short)q1[e]);
      ow0[e] = (short)f2b(f0 + rwb[n * 64 + d16 + e]);
      ow1[e] = (short)f2b(f1 + rwb[n * 64 + d16 + 8 + e]);
      or0[e] = (short)f2b(f0 + rrb[n * 64 + d16 + e]);
      or1[e] = (short)f2b(f1 + rrb[n * 64 + d16 + 8 + e]);
    }
    *(short8v*)&qw_s[il * 72 + d16] = ow0;
    *(short8v*)&qw_s[il * 72 + d16 + 8] = ow1;
    *(short8v*)&qr_s[il * 72 + d16] = or0;
    *(short8v*)&qr_s[il * 72 + d16 + 8] = or1;
  }
  if (tid < 128) {
    int il = tid >> 1, s = tid & 1;
    int t = (it + il) * B + b;
    float acc = 0.0f;
    for (int d = 0; d < 64; ++d)
      acc = fmaf(b2f(qkv[(size_t)t * 2304 + n * 64 + d]) + rsb[n * 64 + d],
                 segemb[(s * H + n) * 64 + d], acc);
    efs[s * 64 + il] = acc;
  }
  if (tid < 64) segrow[tid] = seg_ids[(it + tid) * B + b];

  for (int jt = 0; jt < 512; jt += 64) {
    __syncthreads();
    {
#pragma unroll
      for (int c = 0; c < 2; ++c) {
        int idx = tid + c * 256;
        int row = idx >> 3, k8 = (idx & 7) * 8;
        *(short8v*)&k_s[row * 72 + k8] =
            *(const short8v*)&qkv[(size_t)((jt + row) * B + b) * 2304 + 768 + n * 64 + k8];
      }
      int u0 = 448 - it + jt;
#pragma unroll
      for (int c = 0; c < 4; ++c) {
        int idx = tid + c * 256;
        int row = idx >> 3, k8 = (idx & 7) * 8;
        *(short8v*)&kr_s[row * 72 + k8] =
            *(const short8v*)&krb[(size_t)(u0 + row) * 768 + n * 64 + k8];
      }
    }
    __syncthreads();

    f32x4 aac[4], abd[4][2];
#pragma unroll
    for (int mi = 0; mi < 4; ++mi) {
      aac[mi] = (f32x4){0.f, 0.f, 0.f, 0.f};
      abd[mi][0] = (f32x4){0.f, 0.f, 0.f, 0.f};
      abd[mi][1] = (f32x4){0.f, 0.f, 0.f, 0.f};
    }
#pragma unroll
    for (int ks = 0; ks < 2; ++ks) {
      int kb = ks * 32 + (lane >> 4) * 8;
      short8v aw[4], ar[4];
#pragma unroll
      for (int mi = 0; mi < 4; ++mi) {
        aw[mi] = *(const short8v*)&qw_s[(mi * 16 + (lane & 15)) * 72 + kb];
        ar[mi] = *(const short8v*)&qr_s[(mi * 16 + (lane & 15)) * 72 + kb];
      }
      short8v bk  = *(const short8v*)&k_s[(w * 16 + (lane & 15)) * 72 + kb];
      short8v br0 = *(const short8v*)&kr_s[(w * 32 + (lane & 15)) * 72 + kb];
      short8v br1 = *(const short8v*)&kr_s[(w * 32 + 16 + (lane & 15)) * 72 + kb];
#pragma unroll
      for (int mi = 0; mi < 4; ++mi) {
        aac[mi] = __builtin_amdgcn_mfma_f32_16x16x32_bf16(aw[mi], bk, aac[mi], 0, 0, 0);
        abd[mi][0] = __builtin_amdgcn_mfma_f32_16x16x32_bf16(ar[mi], br0, abd[mi][0], 0, 0, 0);
        abd[mi][1] = __builtin_amdgcn_mfma_f32_16x16x32_bf16(ar[mi], br1, abd[mi][1], 0, 0, 0);
      }
    }
#pragma unroll
    for (int mi = 0; mi < 4; ++mi)
#pragma unroll
      for (int ni = 0; ni < 2; ++ni)
#pragma unroll
        for (int r = 0; r < 4; ++r)
          bd_s[(mi * 16 + (lane >> 4) * 4 + r) * 136 + w * 32 + ni * 16 + (lane & 15)] =
              f2b(abd[mi][ni][r]);
    __syncthreads();

    {
      int jl = w * 16 + (lane & 15);
      int jg = jt + jl;
      float maskterm = -1e30f * (float)input_mask[jg * B + b];
      int segj = seg_ids[jg * B + b];
#pragma unroll
      for (int mi = 0; mi < 4; ++mi)
#pragma unroll
        for (int r = 0; r < 4; ++r) {
          int il = mi * 16 + (lane >> 4) * 4 + r;
          float bd = b2f(bd_s[il * 136 + 64 - il + jl]);
          float e = efs[(segrow[il] != segj ? 1 : 0) * 64 + il];
          sc[il * 512 + jg] = (aac[mi][r] + bd + e) * 0.125f + maskterm;
        }
    }
  }
  __syncthreads();

  int srow = tid >> 2;
  float mx = -3.4e38f;
  {
    int c0 = (tid & 3) * 128;
    for (int c = 0; c < 128; c += 4) {
      float4 vv = *(const float4*)&sc[srow * 512 + c0 + c];
      mx = fmaxf(mx, fmaxf(fmaxf(vv.x, vv.y), fmaxf(vv.z, vv.w)));
    }
    mx = fmaxf(mx, __shfl_xor(mx, 1, 4));
    mx = fmaxf(mx, __shfl_xor(mx, 2, 4));
  }

  f32x4 acc_v[4];
#pragma unroll
  for (int mi = 0; mi < 4; ++mi) acc_v[mi] = (f32x4){0.f, 0.f, 0.f, 0.f};
  float rsum = 0.0f;
  const int vkey = (w & 1) * 8;

  for (int jt = 0; jt < 512; jt += 64) {
    __syncthreads();
    {
      int c16 = (tid & 3) * 16;
#pragma unroll
      for (int half = 0; half < 2; ++half) {
        float4 fa = *(const float4*)&sc[srow * 512 + jt + c16 + half * 8];
        float4 fb = *(const float4*)&sc[srow * 512 + jt + c16 + half * 8 + 4];
        float e0 = __expf(fa.x - mx), e1 = __expf(fa.y - mx);
        float e2 = __expf(fa.z - mx), e3 = __expf(fa.w - mx);
        float e4 = __expf(fb.x - mx), e5 = __expf(fb.y - mx);
        float e6 = __expf(fb.z - mx), e7 = __expf(fb.w - mx);
        rsum += e0 + e1 + e2 + e3 + e4 + e5 + e6 + e7;
        short8v o;
        o[0] = (short)f2b(e0); o[1] = (short)f2b(e1);
        o[2] = (short)f2b(e2); o[3] = (short)f2b(e3);
        o[4] = (short)f2b(e4); o[5] = (short)f2b(e5);
        o[6] = (short)f2b(e6); o[7] = (short)f2b(e7);
        *(short8v*)&pb_s[srow * 72 + c16 + half * 8] = o;
      }
    }
    {
      int vj = tid >> 2, vd16 = (tid & 3) * 16;
      int key = (vd16 & 16) ? 8 : 0;
      short8v v0 = *(const short8v*)&qkv[(size_t)((jt + vj) * B + b) * 2304 + 1536 + n * 64 + vd16];
      short8v v1 = *(const short8v*)&qkv[(size_t)((jt + vj) * B + b) * 2304 + 1536 + n * 64 + vd16 + 8];
#pragma unroll
      for (int e = 0; e < 8; ++e) {
        vt_s[(vd16 + e) * 72 + (vj ^ key)] = (unsigned short)v0[e];
        vt_s[(vd16 + 8 + e) * 72 + (vj ^ key)] = (unsigned short)v1[e];
      }
    }
    __syncthreads();
#pragma unroll
    for (int ks = 0; ks < 2; ++ks) {
      int kb = ks * 32 + (lane >> 4) * 8;
      short8v bv = *(const short8v*)&vt_s[(w * 16 + (lane & 15)) * 72 + (kb ^ vkey)];
#pragma unroll
      for (int mi = 0; mi < 4; ++mi) {
        short8v ap = *(const short8v*)&pb_s[(mi * 16 + (lane & 15)) * 72 + kb];
        acc_v[mi] = __builtin_amdgcn_mfma_f32_16x16x32_bf16(ap, bv, acc_v[mi], 0, 0, 0);
      }
    }
  }
  rsum += __shfl_xor(rsum, 1, 4);
  rsum += __shfl_xor(rsum, 2, 4);
  if ((tid & 3) == 0) rinv_s[srow] = 1.0f / rsum;
  __syncthreads();

#pragma unroll
  for (int mi = 0; mi < 4; ++mi)
#pragma unroll
    for (int r = 0; r < 4; ++r) {
      int row = mi * 16 + (lane >> 4) * 4 + r;
      int d = w * 16 + (lane & 15);
      int t = (it + row) * B + b;
      vec_bf[(size_t)t * D + n * 64 + d] = f2b(acc_v[mi][r] * rinv_s[row]);
    }
}

// ------- fused split-K reduce + bias + residual + layernorm -> h, h_bf --------
template <int P, int HASBIAS>
__global__ __launch_bounds__(256) void add_ln_reduce(const float* __restrict__ part,
                                                     const float* __restrict__ bias,
                                                     float* __restrict__ h,
                                                     unsigned short* __restrict__ h_bf,
                                                     const float* __restrict__ g,
                                                     const float* __restrict__ bi) {
  int t = blockIdx.x;
  int tid = threadIdx.x;
  __shared__ float red[256];
  float v[3];
  float s = 0.0f;
#pragma unroll
  for (int j = 0; j < 3; ++j) {
    int c = tid + j * 256;
    float x = 0.0f;
#pragma unroll
    for (int p = 0; p < P; ++p)
      x += part[(size_t)p * NTOK * D + (size_t)t * D + c];
    if (HASBIAS) x += bias[c];
    v[j] = x + h[(size_t)t * D + c];
    s += v[j];
  }
  red[tid] = s;
  __syncthreads();
  for (int st = 128; st > 0; st >>= 1) {
    if (tid < st) red[tid] += red[tid + st];
    __syncthreads();
  }
  float mu = red[0] / (float)D;
  __syncthreads();
  float s2 = 0.0f;
#pragma unroll
  for (int j = 0; j < 3; ++j) {
    float dd = v[j] - mu;
    s2 += dd * dd;
  }
  red[tid] = s2;
  __syncthreads();
  for (int st = 128; st > 0; st >>= 1) {
    if (tid < st) red[tid] += red[tid + st];
    __syncthreads();
  }
  float var = red[0] / (float)D;
  float rstd = rsqrtf(var + 1e-3f);
  __syncthreads();
#pragma unroll
  for (int j = 0; j < 3; ++j) {
    int c = tid + j * 256;
    float o = (v[j] - mu) * rstd * g[c] + bi[c];
    h[(size_t)t * D + c] = o;
    h_bf[(size_t)t * D + c] = f2b(o);
  }
}

extern "C" void kernel_launch(void* const* d_in, const int* in_sizes, int n_in,
                              void* d_out, int out_size, void* d_ws, size_t ws_size,
                              hipStream_t stream) {
  const int*   inp_k      = (const int*)d_in[0];
  const int*   seg_ids    = (const int*)d_in[1];
  const int*   input_mask = (const int*)d_in[2];
  const float* lut        = (const float*)d_in[3];
  const float* Wq         = (const float*)d_in[4];
  const float* Wk         = (const float*)d_in[5];
  const float* Wv         = (const float*)d_in[6];
  const float* Wr         = (const float*)d_in[7];
  const float* Wo         = (const float*)d_in[8];
  const float* r_w_bias   = (const float*)d_in[9];
  const float* r_r_bias   = (const float*)d_in[10];
  const float* r_s_bias   = (const float*)d_in[11];
  const float* seg_embed  = (const float*)d_in[12];
  const float* ln_attn_g  = (const float*)d_in[13];
  const float* ln_attn_b  = (const float*)d_in[14];
  const float* ln_ff_g    = (const float*)d_in[15];
  const float* ln_ff_b    = (const float*)d_in[16];
  const float* ff_w1      = (const float*)d_in[17];
  const float* ff_b1      = (const float*)d_in[18];
  const float* ff_w2      = (const float*)d_in[19];
  const float* ff_b2      = (const float*)d_in[20];

  float* h = (float*)d_out;
  char* wp = (char*)d_ws;
  auto alloc = [&](size_t bytes) -> void* {
    void* p = (void*)wp;
    wp += (bytes + 255) & ~(size_t)255;
    return p;
  };
  const size_t TOKD = (size_t)NTOK * D;
  const size_t DD = (size_t)D * D;
  const size_t DDI = (size_t)D * DI;
  unsigned short* qkv_bf = (unsigned short*)alloc((size_t)NTOK * 2304 * 2);
  unsigned short* kr_bf  = (unsigned short*)alloc(TOKD * 2);
  unsigned short* h_bf   = (unsigned short*)alloc(TOKD * 2);
  unsigned short* r2_bf  = (unsigned short*)alloc(TOKD * 2);
  unsigned short* vec_bf = (unsigned short*)alloc(TOKD * 2);
  unsigned short* ff1_bf = (unsigned short*)alloc((size_t)NTOK * DI * 2);
  float* scg  = (float*)alloc((size_t)192 * 64 * 512 * 4);
  float* part = (float*)alloc((size_t)4 * TOKD * 4);
  unsigned short* wqkv_t = (unsigned short*)alloc((size_t)NL * 3 * DD * 2);
  unsigned short* wr_t   = (unsigned short*)alloc((size_t)NL * DD * 2);
  unsigned short* wo_bf  = (unsigned short*)alloc((size_t)NL * DD * 2);
  unsigned short* w1_t   = (unsigned short*)alloc((size_t)NL * DDI * 2);
  unsigned short* w2_t   = (unsigned short*)alloc((size_t)NL * DDI * 2);

  prep_all<<<NL * 2016, 256, 0, stream>>>(Wq, Wk, Wv, Wr, Wo, ff_w1, ff_w2,
                                          wqkv_t, wr_t, wo_bf, w1_t, w2_t);
  embed_kernel<<<NTOK, 256, 0, stream>>>(inp_k, lut, h, h_bf);
  posemb_kernel<<<2 * S, 384, 0, stream>>>(r2_bf);

  for (int l = 0; l < NL; ++l) {
    gemm_qkvkr<<<192, 256, 0, stream>>>(h_bf, wqkv_t + (size_t)l * 3 * DD,
                                        r2_bf, wr_t + (size_t)l * DD,
                                        qkv_bf, kr_bf);

    attn_kernel<<<dim3(8, B, H), 256, 0, stream>>>(
        qkv_bf, kr_bf, seg_ids, input_mask,
        r_w_bias + (size_t)l * D, r_r_bias + (size_t)l * D,
        r_s_bias + (size_t)l * D, seg_embed + (size_t)l * 2 * H * DH,
        scg, vec_bf);

    gemm_splitk<<<dim3(6, 8, 2), 256, 0, stream>>>(
        vec_bf, wo_bf + (size_t)l * DD, part, D, D, 384);
    add_ln_reduce<2, 0><<<NTOK, 256, 0, stream>>>(
        part, nullptr, h, h_bf, ln_attn_g + (size_t)l * D, ln_attn_b + (size_t)l * D);

    gemm_bias<1><<<24 * 8, 256, 0, stream>>>(
        h_bf, w1_t + (size_t)l * DDI, ff_b1 + (size_t)l * DI, ff1_bf, DI, D, 24);

    gemm_splitk<<<dim3(6, 8, 4), 256, 0, stream>>>(
        ff1_bf, w2_t + (size_t)l * DDI, part, D, DI, 768);
    add_ln_reduce<4, 1><<<NTOK, 256, 0, stream>>>(
        part, ff_b2 + (size_t)l * D, h, h_bf, ln_ff_g + (size_t)l * D, ln_ff_b + (size_t)l * D);
  }
}

// Round 5
// 1427.245 us; speedup vs baseline: 10.7690x; 1.1493x over previous
//
#include <hip/hip_runtime.h>
#include <hip/hip_bf16.h>
#include <math.h>

#define S 512
#define B 2
#define D 768
#define H 12
#define DH 64
#define DI 3072
#define NL 12
#define NTOK (S * B)   // 1024

typedef __attribute__((ext_vector_type(8))) short short8v;
typedef __attribute__((ext_vector_type(4))) float f32x4;

__device__ __forceinline__ unsigned short f2b(float f) {
  union { float f; unsigned int u; } v; v.f = f;
  unsigned int r = v.u + 0x7fffu + ((v.u >> 16) & 1u);
  return (unsigned short)(r >> 16);
}
__device__ __forceinline__ float b2f(unsigned short u) {
  union { unsigned int u; float f; } v; v.u = ((unsigned int)u) << 16;
  return v.f;
}

__device__ __forceinline__ float gelu_f(float x) {
  const float c = 0.7978845608028654f;  // sqrt(2/pi)
  float t = tanhf(c * (x + 0.044715f * x * x * x));
  return x * 0.5f * (1.0f + t);
}

// ---------------- embedding gather ----------------
__global__ __launch_bounds__(256) void embed_kernel(const int* __restrict__ inp_k,
                                                    const float* __restrict__ lut,
                                                    float* __restrict__ h,
                                                    unsigned short* __restrict__ h_bf) {
  int t = blockIdx.x;
  int id = inp_k[t];
  for (int j = threadIdx.x; j < D; j += 256) {
    float v = lut[(size_t)id * D + j];
    h[t * D + j] = v;
    h_bf[t * D + j] = f2b(v);
  }
}

// ---------------- positional embedding -> bf16 [2S, D] ----------------
__global__ __launch_bounds__(384) void posemb_kernel(unsigned short* __restrict__ r2b) {
  int j = blockIdx.x;
  int d = threadIdx.x;
  float pos = (float)(S - j);
  float inv_freq = expf(-logf(10000.0f) * (2.0f * (float)d / (float)D));
  float x = pos * inv_freq;
  r2b[j * D + d]       = f2b(sinf(x));
  r2b[j * D + 384 + d] = f2b(cosf(x));
}

// ======================= weight prep =========================================
// Weights are stored tile-blocked + XOR-swizzled for linear global_load_lds:
// dst layout: [N/128][K/64] tiles of 8192 ushorts; element (row, k) of a tile
// lives at tilebase + row*64 + (k ^ ((row&7)<<3))  (ushort units).
__device__ __forceinline__ void transpose_swz(const float* __restrict__ src,   // [K][N] row-major
                                              unsigned short* __restrict__ dst,
                                              int K, int N, int tile, int n_base,
                                              unsigned short* __restrict__ Ls /*[64*72]*/) {
  int ntk = K >> 6;
  int tk = tile % ntk, tn = tile / ntk;
  int k0 = tk << 6, n0 = tn << 6;
  int tid = threadIdx.x;
  int kk = tid >> 4, c4 = (tid & 15) * 4;
#pragma unroll
  for (int r = 0; r < 4; ++r) {
    int k = kk + r * 16;
    float4 a = *(const float4*)&src[(size_t)(k0 + k) * N + n0 + c4];
    Ls[(c4 + 0) * 72 + k] = f2b(a.x);
    Ls[(c4 + 1) * 72 + k] = f2b(a.y);
    Ls[(c4 + 2) * 72 + k] = f2b(a.z);
    Ls[(c4 + 3) * 72 + k] = f2b(a.w);
  }
  __syncthreads();
  int nl = tid >> 2, kc0 = (tid & 3) << 4;
  int ng = n_base + n0;
  size_t tilebase = ((size_t)(ng >> 7) * ntk + tk) * 8192;
  int row = (ng & 64) + nl;
  int key = (row & 7) << 3;
  short8v v0 = *(short8v*)&Ls[nl * 72 + kc0];
  short8v v1 = *(short8v*)&Ls[nl * 72 + kc0 + 8];
  *(short8v*)&dst[tilebase + row * 64 + (kc0 ^ key)] = v0;
  *(short8v*)&dst[tilebase + row * 64 + ((kc0 + 8) ^ key)] = v1;
}

// per layer: 432 qkv + 144 wr + 576 w1 + 576 w2 + 144 wo = 1872 blocks
__global__ __launch_bounds__(256) void prep_all(const float* __restrict__ Wq,
                                                const float* __restrict__ Wk,
                                                const float* __restrict__ Wv,
                                                const float* __restrict__ Wr,
                                                const float* __restrict__ Wo,
                                                const float* __restrict__ W1,
                                                const float* __restrict__ W2,
                                                unsigned short* __restrict__ wqkv_t,
                                                unsigned short* __restrict__ wr_t,
                                                unsigned short* __restrict__ wo_t,
                                                unsigned short* __restrict__ w1_t,
                                                unsigned short* __restrict__ w2_t) {
  __shared__ __align__(16) unsigned short Ls[64 * 72];
  const size_t DD = (size_t)D * D;
  const size_t DDI = (size_t)D * DI;
  int tb = blockIdx.x;
  int l = tb / 1872, t2 = tb % 1872;
  int tid = threadIdx.x;
  if (t2 < 432) {
    int which = t2 / 144, tile = t2 % 144;
    const float* src = (which == 0 ? Wq : (which == 1 ? Wk : Wv)) + l * DD;
    transpose_swz(src, wqkv_t + l * 3 * DD, D, D, tile, which * D, Ls);
  } else if (t2 < 576) {
    transpose_swz(Wr + l * DD, wr_t + l * DD, D, D, t2 - 432, 0, Ls);
  } else if (t2 < 1152) {
    transpose_swz(W1 + l * DDI, w1_t + l * DDI, D, DI, t2 - 576, 0, Ls);
  } else if (t2 < 1728) {
    transpose_swz(W2 + l * DDI, w2_t + l * DDI, DI, D, t2 - 1152, 0, Ls);
  } else {
    // Wo: already [N][K]; swizzle-copy, no LDS
    int c = t2 - 1728;
    int tkk = c % 12, tnn = c / 12;
    int k0 = tkk << 6, n0 = tnn << 6;
    int nl = tid >> 2, kc0 = (tid & 3) << 4;
    const float* srcp = Wo + l * DD + (size_t)(n0 + nl) * D + k0 + kc0;
    float4 a0 = *(const float4*)&srcp[0];
    float4 a1 = *(const float4*)&srcp[4];
    float4 a2 = *(const float4*)&srcp[8];
    float4 a3 = *(const float4*)&srcp[12];
    short8v v0, v1;
    v0[0] = (short)f2b(a0.x); v0[1] = (short)f2b(a0.y); v0[2] = (short)f2b(a0.z); v0[3] = (short)f2b(a0.w);
    v0[4] = (short)f2b(a1.x); v0[5] = (short)f2b(a1.y); v0[6] = (short)f2b(a1.z); v0[7] = (short)f2b(a1.w);
    v1[0] = (short)f2b(a2.x); v1[1] = (short)f2b(a2.y); v1[2] = (short)f2b(a2.z); v1[3] = (short)f2b(a2.w);
    v1[4] = (short)f2b(a3.x); v1[5] = (short)f2b(a3.y); v1[6] = (short)f2b(a3.z); v1[7] = (short)f2b(a3.w);
    unsigned short* dst = wo_t + l * DD;
    size_t tilebase = ((size_t)(n0 >> 7) * 12 + tkk) * 8192;
    int row = (n0 & 64) + nl;
    int key = (row & 7) << 3;
    *(short8v*)&dst[tilebase + row * 64 + (kc0 ^ key)] = v0;
    *(short8v*)&dst[tilebase + row * 64 + ((kc0 + 8) ^ key)] = v1;
  }
}

// ======================= MFMA GEMM (global_load_lds + swizzle) ================
// BM=64, BN=128, BK=64, 4 waves. A bf16 [M][K] row-major; Wt pre-swizzled tiles.
// C = A @ W^T over K-range [kbeg, kend).
template <int ACT, int OUTBF>
__device__ __forceinline__ void gemm_tile(const unsigned short* __restrict__ A,
                                          const unsigned short* __restrict__ Wt,
                                          const float* __restrict__ bias,
                                          float* __restrict__ Cf,
                                          unsigned short* __restrict__ Cb,
                                          int N, int K, int bm, int bn,
                                          int kbeg, int kend) {
  __shared__ __align__(16) unsigned short As[64 * 64];    // 8 KB linear (swizzled content)
  __shared__ __align__(16) unsigned short Bs[128 * 64];   // 16 KB linear (swizzled content)
  const int tid = threadIdx.x, lane = tid & 63, w = tid >> 6;
  const int l8 = lane >> 3, lm8 = lane & 7;
  const int aColByte = ((lm8 ^ l8) << 4);   // pre-swizzled source column (bytes in 128B row)
  const int KT = K >> 6;
  const size_t wtn = (size_t)(bn >> 7) * KT;

  f32x4 acc[4][2];
#pragma unroll
  for (int mi = 0; mi < 4; ++mi)
#pragma unroll
    for (int ni = 0; ni < 2; ++ni)
      acc[mi][ni] = (f32x4){0.f, 0.f, 0.f, 0.f};

  for (int kt = kbeg; kt < kend; kt += 64) {
    __syncthreads();
    // stage A: 2 calls x 4 waves x 64 lanes x 16B = 8 KB
#pragma unroll
    for (int c = 0; c < 2; ++c) {
      int row = c * 32 + w * 8 + l8;
      const char* src = (const char*)&A[(size_t)(bm + row) * K + kt] + aColByte;
      __builtin_amdgcn_global_load_lds(
          (const __attribute__((address_space(1))) void*)src,
          (__attribute__((address_space(3))) void*)((char*)As + c * 4096 + w * 1024),
          16, 0, 0);
    }
    // stage B: 4 calls, fully linear from pre-swizzled tile
    const char* wt = (const char*)&Wt[(wtn + (kt >> 6)) * 8192];
#pragma unroll
    for (int c = 0; c < 4; ++c) {
      __builtin_amdgcn_global_load_lds(
          (const __attribute__((address_space(1))) void*)(wt + c * 4096 + w * 1024 + lane * 16),
          (__attribute__((address_space(3))) void*)((char*)Bs + c * 4096 + w * 1024),
          16, 0, 0);
    }
    __syncthreads();   // compiler drains vmcnt(0) here -> LDS ready
#pragma unroll
    for (int ks = 0; ks < 2; ++ks) {
      const int kus = ks * 32 + (lane >> 4) * 8;
      short8v af[4], bf[2];
#pragma unroll
      for (int mi = 0; mi < 4; ++mi) {
        int row = mi * 16 + (lane & 15);
        af[mi] = *(const short8v*)&As[row * 64 + (kus ^ ((row & 7) << 3))];
      }
#pragma unroll
      for (int ni = 0; ni < 2; ++ni) {
        int row = w * 32 + ni * 16 + (lane & 15);
        bf[ni] = *(const short8v*)&Bs[row * 64 + (kus ^ ((row & 7) << 3))];
      }
#pragma unroll
      for (int mi = 0; mi < 4; ++mi)
#pragma unroll
        for (int ni = 0; ni < 2; ++ni)
          acc[mi][ni] = __builtin_amdgcn_mfma_f32_16x16x32_bf16(af[mi], bf[ni], acc[mi][ni], 0, 0, 0);
    }
  }

  int r0 = (lane >> 4) * 4, cc = lane & 15;
#pragma unroll
  for (int mi = 0; mi < 4; ++mi) {
    int row = bm + mi * 16 + r0;
#pragma unroll
    for (int ni = 0; ni < 2; ++ni) {
      int col = bn + w * 32 + ni * 16 + cc;
      float bv = bias ? bias[col] : 0.0f;
#pragma unroll
      for (int r = 0; r < 4; ++r) {
        float v = acc[mi][ni][r] + bv;
        if (ACT == 1) v = gelu_f(v);
        if (OUTBF) Cb[(size_t)(row + r) * N + col] = f2b(v);
        else       Cf[(size_t)(row + r) * N + col] = v;
      }
    }
  }
}

// merged qkv + kr projection: grid.x = 288 + 96 = 384
__global__ __launch_bounds__(256) void gemm_qkvkr(const unsigned short* __restrict__ h_bf,
                                                  const unsigned short* __restrict__ wqkv,
                                                  const unsigned short* __restrict__ r2_bf,
                                                  const unsigned short* __restrict__ wr,
                                                  unsigned short* __restrict__ qkv_bf,
                                                  unsigned short* __restrict__ kr_bf) {
  int bx = blockIdx.x;
  const unsigned short *A, *W;
  unsigned short* C;
  int N, bm, bn;
  if (bx < 288) {
    A = h_bf; W = wqkv; C = qkv_bf; N = 2304;
    bm = (bx / 18) * 64; bn = (bx % 18) * 128;
  } else {
    int b2 = bx - 288;
    A = r2_bf; W = wr; C = kr_bf; N = 768;
    bm = (b2 / 6) * 64; bn = (b2 % 6) * 128;
  }
  gemm_tile<0, 1>(A, W, nullptr, nullptr, C, N, 768, bm, bn, 0, 768);
}

// bf16-out GEMM with bias/act: grid.x = ncb * (M/64)
template <int ACT>
__global__ __launch_bounds__(256) void gemm_bias(const unsigned short* __restrict__ A,
                                                 const unsigned short* __restrict__ W,
                                                 const float* __restrict__ bias,
                                                 unsigned short* __restrict__ C,
                                                 int N, int K, int ncb) {
  int bx = blockIdx.x;
  gemm_tile<ACT, 1>(A, W, bias, nullptr, C, N, K, (bx / ncb) * 64, (bx % ncb) * 128, 0, K);
}

// split-K GEMM -> f32 partials. grid = (N/128, M/64, KS), kch = K/KS
__global__ __launch_bounds__(256) void gemm_splitk(const unsigned short* __restrict__ A,
                                                   const unsigned short* __restrict__ W,
                                                   float* __restrict__ part,
                                                   int N, int K, int kch) {
  int kz = blockIdx.z;
  float* Cf = part + (size_t)kz * NTOK * N;
  gemm_tile<0, 0>(A, W, nullptr, Cf, nullptr, N, K,
                  blockIdx.y * 64, blockIdx.x * 128, kz * kch, (kz + 1) * kch);
}

// ---------------- MFMA fused attention (unchanged) ----------------------------
__global__ __launch_bounds__(256) void attn_kernel(const unsigned short* __restrict__ qkv,
                                                   const unsigned short* __restrict__ krb,
                                                   const int* __restrict__ seg_ids,
                                                   const int* __restrict__ input_mask,
                                                   const float* __restrict__ rwb,
                                                   const float* __restrict__ rrb,
                                                   const float* __restrict__ rsb,
                                                   const float* __restrict__ segemb,
                                                   float* __restrict__ scg,
                                                   unsigned short* __restrict__ vec_bf) {
  __shared__ __align__(16) char smem[64512];
  unsigned short* qw_s = (unsigned short*)(smem + 0);      // [64][72]
  unsigned short* qr_s = (unsigned short*)(smem + 9216);   // [64][72]
  unsigned short* k_s  = (unsigned short*)(smem + 18432);  // [64][72]
  unsigned short* kr_s = (unsigned short*)(smem + 27648);  // [128][72]
  unsigned short* bd_s = (unsigned short*)(smem + 46080);  // [64][136]
  float* efs    = (float*)(smem + 63488);                  // [2][64]
  float* rinv_s = (float*)(smem + 64000);                  // [64]
  int*   segrow = (int*)(smem + 64256);                    // [64]
  unsigned short* pb_s = (unsigned short*)(smem + 0);      // [64][72] (aliases qw_s)
  unsigned short* vt_s = (unsigned short*)(smem + 9216);   // [64][72] (aliases qr_s)

  const int it = blockIdx.x * 64, b = blockIdx.y, n = blockIdx.z;
  const int tid = threadIdx.x, lane = tid & 63, w = tid >> 6;
  float* sc = scg + (size_t)((blockIdx.z * 2 + blockIdx.y) * 8 + blockIdx.x) * (64 * 512);

  {
    int il = tid >> 2, d16 = (tid & 3) * 16;
    int t = (it + il) * B + b;
    short8v q0 = *(const short8v*)&qkv[(size_t)t * 2304 + n * 64 + d16];
    short8v q1 = *(const short8v*)&qkv[(size_t)t * 2304 + n * 64 + d16 + 8];
    short8v ow0, ow1, or0, or1;
#pragma unroll
    for (int e = 0; e < 8; ++e) {
      float f0 = b2f((unsigned short)q0[e]);
      float f1 = b2f((unsigned short)q1[e]);
      ow0[e] = (short)f2b(f0 + rwb[n * 64 + d16 + e]);
      ow1[e] = (short)f2b(f1 + rwb[n * 64 + d16 + 8 + e]);
      or0[e] = (short)f2b(f0 + rrb[n * 64 + d16 + e]);
      or1[e] = (short)f2b(f1 + rrb[n * 64 + d16 + 8 + e]);
    }
    *(short8v*)&qw_s[il * 72 + d16] = ow0;
    *(short8v*)&qw_s[il * 72 + d16 + 8] = ow1;
    *(short8v*)&qr_s[il * 72 + d16] = or0;
    *(short8v*)&qr_s[il * 72 + d16 + 8] = or1;
  }
  if (tid < 128) {
    int il = tid >> 1, s = tid & 1;
    int t = (it + il) * B + b;
    float acc = 0.0f;
    for (int d = 0; d < 64; ++d)
      acc = fmaf(b2f(qkv[(size_t)t * 2304 + n * 64 + d]) + rsb[n * 64 + d],
                 segemb[(s * H + n) * 64 + d], acc);
    efs[s * 64 + il] = acc;
  }
  if (tid < 64) segrow[tid] = seg_ids[(it + tid) * B + b];

  for (int jt = 0; jt < 512; jt += 64) {
    __syncthreads();
    {
#pragma unroll
      for (int c = 0; c < 2; ++c) {
        int idx = tid + c * 256;
        int row = idx >> 3, k8 = (idx & 7) * 8;
        *(short8v*)&k_s[row * 72 + k8] =
            *(const short8v*)&qkv[(size_t)((jt + row) * B + b) * 2304 + 768 + n * 64 + k8];
      }
      int u0 = 448 - it + jt;
#pragma unroll
      for (int c = 0; c < 4; ++c) {
        int idx = tid + c * 256;
        int row = idx >> 3, k8 = (idx & 7) * 8;
        *(short8v*)&kr_s[row * 72 + k8] =
            *(const short8v*)&krb[(size_t)(u0 + row) * 768 + n * 64 + k8];
      }
    }
    __syncthreads();

    f32x4 aac[4], abd[4][2];
#pragma unroll
    for (int mi = 0; mi < 4; ++mi) {
      aac[mi] = (f32x4){0.f, 0.f, 0.f, 0.f};
      abd[mi][0] = (f32x4){0.f, 0.f, 0.f, 0.f};
      abd[mi][1] = (f32x4){0.f, 0.f, 0.f, 0.f};
    }
#pragma unroll
    for (int ks = 0; ks < 2; ++ks) {
      int kb = ks * 32 + (lane >> 4) * 8;
      short8v aw[4], ar[4];
#pragma unroll
      for (int mi = 0; mi < 4; ++mi) {
        aw[mi] = *(const short8v*)&qw_s[(mi * 16 + (lane & 15)) * 72 + kb];
        ar[mi] = *(const short8v*)&qr_s[(mi * 16 + (lane & 15)) * 72 + kb];
      }
      short8v bk  = *(const short8v*)&k_s[(w * 16 + (lane & 15)) * 72 + kb];
      short8v br0 = *(const short8v*)&kr_s[(w * 32 + (lane & 15)) * 72 + kb];
      short8v br1 = *(const short8v*)&kr_s[(w * 32 + 16 + (lane & 15)) * 72 + kb];
#pragma unroll
      for (int mi = 0; mi < 4; ++mi) {
        aac[mi] = __builtin_amdgcn_mfma_f32_16x16x32_bf16(aw[mi], bk, aac[mi], 0, 0, 0);
        abd[mi][0] = __builtin_amdgcn_mfma_f32_16x16x32_bf16(ar[mi], br0, abd[mi][0], 0, 0, 0);
        abd[mi][1] = __builtin_amdgcn_mfma_f32_16x16x32_bf16(ar[mi], br1, abd[mi][1], 0, 0, 0);
      }
    }
#pragma unroll
    for (int mi = 0; mi < 4; ++mi)
#pragma unroll
      for (int ni = 0; ni < 2; ++ni)
#pragma unroll
        for (int r = 0; r < 4; ++r)
          bd_s[(mi * 16 + (lane >> 4) * 4 + r) * 136 + w * 32 + ni * 16 + (lane & 15)] =
              f2b(abd[mi][ni][r]);
    __syncthreads();

    {
      int jl = w * 16 + (lane & 15);
      int jg = jt + jl;
      float maskterm = -1e30f * (float)input_mask[jg * B + b];
      int segj = seg_ids[jg * B + b];
#pragma unroll
      for (int mi = 0; mi < 4; ++mi)
#pragma unroll
        for (int r = 0; r < 4; ++r) {
          int il = mi * 16 + (lane >> 4) * 4 + r;
          float bd = b2f(bd_s[il * 136 + 64 - il + jl]);
          float e = efs[(segrow[il] != segj ? 1 : 0) * 64 + il];
          sc[il * 512 + jg] = (aac[mi][r] + bd + e) * 0.125f + maskterm;
        }
    }
  }
  __syncthreads();

  int srow = tid >> 2;
  float mx = -3.4e38f;
  {
    int c0 = (tid & 3) * 128;
    for (int c = 0; c < 128; c += 4) {
      float4 vv = *(const float4*)&sc[srow * 512 + c0 + c];
      mx = fmaxf(mx, fmaxf(fmaxf(vv.x, vv.y), fmaxf(vv.z, vv.w)));
    }
    mx = fmaxf(mx, __shfl_xor(mx, 1, 4));
    mx = fmaxf(mx, __shfl_xor(mx, 2, 4));
  }

  f32x4 acc_v[4];
#pragma unroll
  for (int mi = 0; mi < 4; ++mi) acc_v[mi] = (f32x4){0.f, 0.f, 0.f, 0.f};
  float rsum = 0.0f;
  const int vkey = (w & 1) * 8;

  for (int jt = 0; jt < 512; jt += 64) {
    __syncthreads();
    {
      int c16 = (tid & 3) * 16;
#pragma unroll
      for (int half = 0; half < 2; ++half) {
        float4 fa = *(const float4*)&sc[srow * 512 + jt + c16 + half * 8];
        float4 fb = *(const float4*)&sc[srow * 512 + jt + c16 + half * 8 + 4];
        float e0 = __expf(fa.x - mx), e1 = __expf(fa.y - mx);
        float e2 = __expf(fa.z - mx), e3 = __expf(fa.w - mx);
        float e4 = __expf(fb.x - mx), e5 = __expf(fb.y - mx);
        float e6 = __expf(fb.z - mx), e7 = __expf(fb.w - mx);
        rsum += e0 + e1 + e2 + e3 + e4 + e5 + e6 + e7;
        short8v o;
        o[0] = (short)f2b(e0); o[1] = (short)f2b(e1);
        o[2] = (short)f2b(e2); o[3] = (short)f2b(e3);
        o[4] = (short)f2b(e4); o[5] = (short)f2b(e5);
        o[6] = (short)f2b(e6); o[7] = (short)f2b(e7);
        *(short8v*)&pb_s[srow * 72 + c16 + half * 8] = o;
      }
    }
    {
      int vj = tid >> 2, vd16 = (tid & 3) * 16;
      int key = (vd16 & 16) ? 8 : 0;
      short8v v0 = *(const short8v*)&qkv[(size_t)((jt + vj) * B + b) * 2304 + 1536 + n * 64 + vd16];
      short8v v1 = *(const short8v*)&qkv[(size_t)((jt + vj) * B + b) * 2304 + 1536 + n * 64 + vd16 + 8];
#pragma unroll
      for (int e = 0; e < 8; ++e) {
        vt_s[(vd16 + e) * 72 + (vj ^ key)] = (unsigned short)v0[e];
        vt_s[(vd16 + 8 + e) * 72 + (vj ^ key)] = (unsigned short)v1[e];
      }
    }
    __syncthreads();
#pragma unroll
    for (int ks = 0; ks < 2; ++ks) {
      int kb = ks * 32 + (lane >> 4) * 8;
      short8v bv = *(const short8v*)&vt_s[(w * 16 + (lane & 15)) * 72 + (kb ^ vkey)];
#pragma unroll
      for (int mi = 0; mi < 4; ++mi) {
        short8v ap = *(const short8v*)&pb_s[(mi * 16 + (lane & 15)) * 72 + kb];
        acc_v[mi] = __builtin_amdgcn_mfma_f32_16x16x32_bf16(ap, bv, acc_v[mi], 0, 0, 0);
      }
    }
  }
  rsum += __shfl_xor(rsum, 1, 4);
  rsum += __shfl_xor(rsum, 2, 4);
  if ((tid & 3) == 0) rinv_s[srow] = 1.0f / rsum;
  __syncthreads();

#pragma unroll
  for (int mi = 0; mi < 4; ++mi)
#pragma unroll
    for (int r = 0; r < 4; ++r) {
      int row = mi * 16 + (lane >> 4) * 4 + r;
      int d = w * 16 + (lane & 15);
      int t = (it + row) * B + b;
      vec_bf[(size_t)t * D + n * 64 + d] = f2b(acc_v[mi][r] * rinv_s[row]);
    }
}

// ------- fused split-K reduce + bias + residual + layernorm -> h, h_bf --------
template <int P, int HASBIAS>
__global__ __launch_bounds__(256) void add_ln_reduce(const float* __restrict__ part,
                                                     const float* __restrict__ bias,
                                                     float* __restrict__ h,
                                                     unsigned short* __restrict__ h_bf,
                                                     const float* __restrict__ g,
                                                     const float* __restrict__ bi) {
  int t = blockIdx.x;
  int tid = threadIdx.x;
  __shared__ float red[256];
  float v[3];
  float s = 0.0f;
#pragma unroll
  for (int j = 0; j < 3; ++j) {
    int c = tid + j * 256;
    float x = 0.0f;
#pragma unroll
    for (int p = 0; p < P; ++p)
      x += part[(size_t)p * NTOK * D + (size_t)t * D + c];
    if (HASBIAS) x += bias[c];
    v[j] = x + h[(size_t)t * D + c];
    s += v[j];
  }
  red[tid] = s;
  __syncthreads();
  for (int st = 128; st > 0; st >>= 1) {
    if (tid < st) red[tid] += red[tid + st];
    __syncthreads();
  }
  float mu = red[0] / (float)D;
  __syncthreads();
  float s2 = 0.0f;
#pragma unroll
  for (int j = 0; j < 3; ++j) {
    float dd = v[j] - mu;
    s2 += dd * dd;
  }
  red[tid] = s2;
  __syncthreads();
  for (int st = 128; st > 0; st >>= 1) {
    if (tid < st) red[tid] += red[tid + st];
    __syncthreads();
  }
  float var = red[0] / (float)D;
  float rstd = rsqrtf(var + 1e-3f);
  __syncthreads();
#pragma unroll
  for (int j = 0; j < 3; ++j) {
    int c = tid + j * 256;
    float o = (v[j] - mu) * rstd * g[c] + bi[c];
    h[(size_t)t * D + c] = o;
    h_bf[(size_t)t * D + c] = f2b(o);
  }
}

extern "C" void kernel_launch(void* const* d_in, const int* in_sizes, int n_in,
                              void* d_out, int out_size, void* d_ws, size_t ws_size,
                              hipStream_t stream) {
  const int*   inp_k      = (const int*)d_in[0];
  const int*   seg_ids    = (const int*)d_in[1];
  const int*   input_mask = (const int*)d_in[2];
  const float* lut        = (const float*)d_in[3];
  const float* Wq         = (const float*)d_in[4];
  const float* Wk         = (const float*)d_in[5];
  const float* Wv         = (const float*)d_in[6];
  const float* Wr         = (const float*)d_in[7];
  const float* Wo         = (const float*)d_in[8];
  const float* r_w_bias   = (const float*)d_in[9];
  const float* r_r_bias   = (const float*)d_in[10];
  const float* r_s_bias   = (const float*)d_in[11];
  const float* seg_embed  = (const float*)d_in[12];
  const float* ln_attn_g  = (const float*)d_in[13];
  const float* ln_attn_b  = (const float*)d_in[14];
  const float* ln_ff_g    = (const float*)d_in[15];
  const float* ln_ff_b    = (const float*)d_in[16];
  const float* ff_w1      = (const float*)d_in[17];
  const float* ff_b1      = (const float*)d_in[18];
  const float* ff_w2      = (const float*)d_in[19];
  const float* ff_b2      = (const float*)d_in[20];

  float* h = (float*)d_out;
  char* wp = (char*)d_ws;
  auto alloc = [&](size_t bytes) -> void* {
    void* p = (void*)wp;
    wp += (bytes + 255) & ~(size_t)255;
    return p;
  };
  const size_t TOKD = (size_t)NTOK * D;
  const size_t DD = (size_t)D * D;
  const size_t DDI = (size_t)D * DI;
  unsigned short* qkv_bf = (unsigned short*)alloc((size_t)NTOK * 2304 * 2);
  unsigned short* kr_bf  = (unsigned short*)alloc(TOKD * 2);
  unsigned short* h_bf   = (unsigned short*)alloc(TOKD * 2);
  unsigned short* r2_bf  = (unsigned short*)alloc(TOKD * 2);
  unsigned short* vec_bf = (unsigned short*)alloc(TOKD * 2);
  unsigned short* ff1_bf = (unsigned short*)alloc((size_t)NTOK * DI * 2);
  float* scg  = (float*)alloc((size_t)192 * 64 * 512 * 4);
  float* part = (float*)alloc((size_t)4 * TOKD * 4);
  unsigned short* wqkv_t = (unsigned short*)alloc((size_t)NL * 3 * DD * 2);
  unsigned short* wr_t   = (unsigned short*)alloc((size_t)NL * DD * 2);
  unsigned short* wo_t   = (unsigned short*)alloc((size_t)NL * DD * 2);
  unsigned short* w1_t   = (unsigned short*)alloc((size_t)NL * DDI * 2);
  unsigned short* w2_t   = (unsigned short*)alloc((size_t)NL * DDI * 2);

  prep_all<<<NL * 1872, 256, 0, stream>>>(Wq, Wk, Wv, Wr, Wo, ff_w1, ff_w2,
                                          wqkv_t, wr_t, wo_t, w1_t, w2_t);
  embed_kernel<<<NTOK, 256, 0, stream>>>(inp_k, lut, h, h_bf);
  posemb_kernel<<<2 * S, 384, 0, stream>>>(r2_bf);

  for (int l = 0; l < NL; ++l) {
    gemm_qkvkr<<<384, 256, 0, stream>>>(h_bf, wqkv_t + (size_t)l * 3 * DD,
                                        r2_bf, wr_t + (size_t)l * DD,
                                        qkv_bf, kr_bf);

    attn_kernel<<<dim3(8, B, H), 256, 0, stream>>>(
        qkv_bf, kr_bf, seg_ids, input_mask,
        r_w_bias + (size_t)l * D, r_r_bias + (size_t)l * D,
        r_s_bias + (size_t)l * D, seg_embed + (size_t)l * 2 * H * DH,
        scg, vec_bf);

    gemm_splitk<<<dim3(6, 16, 2), 256, 0, stream>>>(
        vec_bf, wo_t + (size_t)l * DD, part, D, D, 384);
    add_ln_reduce<2, 0><<<NTOK, 256, 0, stream>>>(
        part, nullptr, h, h_bf, ln_attn_g + (size_t)l * D, ln_attn_b + (size_t)l * D);

    gemm_bias<1><<<24 * 16, 256, 0, stream>>>(
        h_bf, w1_t + (size_t)l * DDI, ff_b1 + (size_t)l * DI, ff1_bf, DI, D, 24);

    gemm_splitk<<<dim3(6, 16, 4), 256, 0, stream>>>(
        ff1_bf, w2_t + (size_t)l * DDI, part, D, DI, 768);
    add_ln_reduce<4, 1><<<NTOK, 256, 0, stream>>>(
        part, ff_b2 + (size_t)l * D, h, h_bf, ln_ff_g + (size_t)l * D, ln_ff_b + (size_t)l * D);
  }
}

// Round 6
// 1323.155 us; speedup vs baseline: 11.6162x; 1.0787x over previous
//
#include <hip/hip_runtime.h>
#include <hip/hip_bf16.h>
#include <math.h>

#define S 512
#define B 2
#define D 768
#define H 12
#define DH 64
#define DI 3072
#define NL 12
#define NTOK (S * B)   // 1024

typedef __attribute__((ext_vector_type(8))) short short8v;
typedef __attribute__((ext_vector_type(4))) float f32x4;

__device__ __forceinline__ unsigned short f2b(float f) {
  union { float f; unsigned int u; } v; v.f = f;
  unsigned int r = v.u + 0x7fffu + ((v.u >> 16) & 1u);
  return (unsigned short)(r >> 16);
}
__device__ __forceinline__ float b2f(unsigned short u) {
  union { unsigned int u; float f; } v; v.u = ((unsigned int)u) << 16;
  return v.f;
}

__device__ __forceinline__ float gelu_f(float x) {
  const float c = 0.7978845608028654f;  // sqrt(2/pi)
  float t = tanhf(c * (x + 0.044715f * x * x * x));
  return x * 0.5f * (1.0f + t);
}

// xor swizzle key for [64][64] bf16 LDS tiles (8-ushort granular)
__device__ __forceinline__ int vkey(int r) {
  return (((r & 7) ^ ((r >> 3) & 7)) << 3);
}

// ---------------- embedding gather ----------------
__global__ __launch_bounds__(256) void embed_kernel(const int* __restrict__ inp_k,
                                                    const float* __restrict__ lut,
                                                    float* __restrict__ h,
                                                    unsigned short* __restrict__ h_bf) {
  int t = blockIdx.x;
  int id = inp_k[t];
  for (int j = threadIdx.x; j < D; j += 256) {
    float v = lut[(size_t)id * D + j];
    h[t * D + j] = v;
    h_bf[t * D + j] = f2b(v);
  }
}

// ---------------- positional embedding -> bf16 [2S, D] ----------------
__global__ __launch_bounds__(384) void posemb_kernel(unsigned short* __restrict__ r2b) {
  int j = blockIdx.x;
  int d = threadIdx.x;
  float pos = (float)(S - j);
  float inv_freq = expf(-logf(10000.0f) * (2.0f * (float)d / (float)D));
  float x = pos * inv_freq;
  r2b[j * D + d]       = f2b(sinf(x));
  r2b[j * D + 384 + d] = f2b(cosf(x));
}

// ======================= weight prep (unchanged) ==============================
__device__ __forceinline__ void transpose_swz(const float* __restrict__ src,   // [K][N] row-major
                                              unsigned short* __restrict__ dst,
                                              int K, int N, int tile, int n_base,
                                              unsigned short* __restrict__ Ls /*[64*72]*/) {
  int ntk = K >> 6;
  int tk = tile % ntk, tn = tile / ntk;
  int k0 = tk << 6, n0 = tn << 6;
  int tid = threadIdx.x;
  int kk = tid >> 4, c4 = (tid & 15) * 4;
#pragma unroll
  for (int r = 0; r < 4; ++r) {
    int k = kk + r * 16;
    float4 a = *(const float4*)&src[(size_t)(k0 + k) * N + n0 + c4];
    Ls[(c4 + 0) * 72 + k] = f2b(a.x);
    Ls[(c4 + 1) * 72 + k] = f2b(a.y);
    Ls[(c4 + 2) * 72 + k] = f2b(a.z);
    Ls[(c4 + 3) * 72 + k] = f2b(a.w);
  }
  __syncthreads();
  int nl = tid >> 2, kc0 = (tid & 3) << 4;
  int ng = n_base + n0;
  size_t tilebase = ((size_t)(ng >> 7) * ntk + tk) * 8192;
  int row = (ng & 64) + nl;
  int key = (row & 7) << 3;
  short8v v0 = *(short8v*)&Ls[nl * 72 + kc0];
  short8v v1 = *(short8v*)&Ls[nl * 72 + kc0 + 8];
  *(short8v*)&dst[tilebase + row * 64 + (kc0 ^ key)] = v0;
  *(short8v*)&dst[tilebase + row * 64 + ((kc0 + 8) ^ key)] = v1;
}

// per layer: 432 qkv + 144 wr + 576 w1 + 576 w2 + 144 wo = 1872 blocks
__global__ __launch_bounds__(256) void prep_all(const float* __restrict__ Wq,
                                                const float* __restrict__ Wk,
                                                const float* __restrict__ Wv,
                                                const float* __restrict__ Wr,
                                                const float* __restrict__ Wo,
                                                const float* __restrict__ W1,
                                                const float* __restrict__ W2,
                                                unsigned short* __restrict__ wqkv_t,
                                                unsigned short* __restrict__ wr_t,
                                                unsigned short* __restrict__ wo_t,
                                                unsigned short* __restrict__ w1_t,
                                                unsigned short* __restrict__ w2_t) {
  __shared__ __align__(16) unsigned short Ls[64 * 72];
  const size_t DD = (size_t)D * D;
  const size_t DDI = (size_t)D * DI;
  int tb = blockIdx.x;
  int l = tb / 1872, t2 = tb % 1872;
  int tid = threadIdx.x;
  if (t2 < 432) {
    int which = t2 / 144, tile = t2 % 144;
    const float* src = (which == 0 ? Wq : (which == 1 ? Wk : Wv)) + l * DD;
    transpose_swz(src, wqkv_t + l * 3 * DD, D, D, tile, which * D, Ls);
  } else if (t2 < 576) {
    transpose_swz(Wr + l * DD, wr_t + l * DD, D, D, t2 - 432, 0, Ls);
  } else if (t2 < 1152) {
    transpose_swz(W1 + l * DDI, w1_t + l * DDI, D, DI, t2 - 576, 0, Ls);
  } else if (t2 < 1728) {
    transpose_swz(W2 + l * DDI, w2_t + l * DDI, DI, D, t2 - 1152, 0, Ls);
  } else {
    // Wo: already [N][K]; swizzle-copy, no LDS
    int c = t2 - 1728;
    int tkk = c % 12, tnn = c / 12;
    int k0 = tkk << 6, n0 = tnn << 6;
    int nl = tid >> 2, kc0 = (tid & 3) << 4;
    const float* srcp = Wo + l * DD + (size_t)(n0 + nl) * D + k0 + kc0;
    float4 a0 = *(const float4*)&srcp[0];
    float4 a1 = *(const float4*)&srcp[4];
    float4 a2 = *(const float4*)&srcp[8];
    float4 a3 = *(const float4*)&srcp[12];
    short8v v0, v1;
    v0[0] = (short)f2b(a0.x); v0[1] = (short)f2b(a0.y); v0[2] = (short)f2b(a0.z); v0[3] = (short)f2b(a0.w);
    v0[4] = (short)f2b(a1.x); v0[5] = (short)f2b(a1.y); v0[6] = (short)f2b(a1.z); v0[7] = (short)f2b(a1.w);
    v1[0] = (short)f2b(a2.x); v1[1] = (short)f2b(a2.y); v1[2] = (short)f2b(a2.z); v1[3] = (short)f2b(a2.w);
    v1[4] = (short)f2b(a3.x); v1[5] = (short)f2b(a3.y); v1[6] = (short)f2b(a3.z); v1[7] = (short)f2b(a3.w);
    unsigned short* dst = wo_t + l * DD;
    size_t tilebase = ((size_t)(n0 >> 7) * 12 + tkk) * 8192;
    int row = (n0 & 64) + nl;
    int key = (row & 7) << 3;
    *(short8v*)&dst[tilebase + row * 64 + (kc0 ^ key)] = v0;
    *(short8v*)&dst[tilebase + row * 64 + ((kc0 + 8) ^ key)] = v1;
  }
}

// ======================= MFMA GEMM (global_load_lds + swizzle, unchanged) =====
template <int ACT, int OUTBF>
__device__ __forceinline__ void gemm_tile(const unsigned short* __restrict__ A,
                                          const unsigned short* __restrict__ Wt,
                                          const float* __restrict__ bias,
                                          float* __restrict__ Cf,
                                          unsigned short* __restrict__ Cb,
                                          int N, int K, int bm, int bn,
                                          int kbeg, int kend) {
  __shared__ __align__(16) unsigned short As[64 * 64];
  __shared__ __align__(16) unsigned short Bs[128 * 64];
  const int tid = threadIdx.x, lane = tid & 63, w = tid >> 6;
  const int l8 = lane >> 3, lm8 = lane & 7;
  const int aColByte = ((lm8 ^ l8) << 4);
  const int KT = K >> 6;
  const size_t wtn = (size_t)(bn >> 7) * KT;

  f32x4 acc[4][2];
#pragma unroll
  for (int mi = 0; mi < 4; ++mi)
#pragma unroll
    for (int ni = 0; ni < 2; ++ni)
      acc[mi][ni] = (f32x4){0.f, 0.f, 0.f, 0.f};

  for (int kt = kbeg; kt < kend; kt += 64) {
    __syncthreads();
#pragma unroll
    for (int c = 0; c < 2; ++c) {
      int row = c * 32 + w * 8 + l8;
      const char* src = (const char*)&A[(size_t)(bm + row) * K + kt] + aColByte;
      __builtin_amdgcn_global_load_lds(
          (const __attribute__((address_space(1))) void*)src,
          (__attribute__((address_space(3))) void*)((char*)As + c * 4096 + w * 1024),
          16, 0, 0);
    }
    const char* wt = (const char*)&Wt[(wtn + (kt >> 6)) * 8192];
#pragma unroll
    for (int c = 0; c < 4; ++c) {
      __builtin_amdgcn_global_load_lds(
          (const __attribute__((address_space(1))) void*)(wt + c * 4096 + w * 1024 + lane * 16),
          (__attribute__((address_space(3))) void*)((char*)Bs + c * 4096 + w * 1024),
          16, 0, 0);
    }
    __syncthreads();
#pragma unroll
    for (int ks = 0; ks < 2; ++ks) {
      const int kus = ks * 32 + (lane >> 4) * 8;
      short8v af[4], bf[2];
#pragma unroll
      for (int mi = 0; mi < 4; ++mi) {
        int row = mi * 16 + (lane & 15);
        af[mi] = *(const short8v*)&As[row * 64 + (kus ^ ((row & 7) << 3))];
      }
#pragma unroll
      for (int ni = 0; ni < 2; ++ni) {
        int row = w * 32 + ni * 16 + (lane & 15);
        bf[ni] = *(const short8v*)&Bs[row * 64 + (kus ^ ((row & 7) << 3))];
      }
#pragma unroll
      for (int mi = 0; mi < 4; ++mi)
#pragma unroll
        for (int ni = 0; ni < 2; ++ni)
          acc[mi][ni] = __builtin_amdgcn_mfma_f32_16x16x32_bf16(af[mi], bf[ni], acc[mi][ni], 0, 0, 0);
    }
  }

  int r0 = (lane >> 4) * 4, cc = lane & 15;
#pragma unroll
  for (int mi = 0; mi < 4; ++mi) {
    int row = bm + mi * 16 + r0;
#pragma unroll
    for (int ni = 0; ni < 2; ++ni) {
      int col = bn + w * 32 + ni * 16 + cc;
      float bv = bias ? bias[col] : 0.0f;
#pragma unroll
      for (int r = 0; r < 4; ++r) {
        float v = acc[mi][ni][r] + bv;
        if (ACT == 1) v = gelu_f(v);
        if (OUTBF) Cb[(size_t)(row + r) * N + col] = f2b(v);
        else       Cf[(size_t)(row + r) * N + col] = v;
      }
    }
  }
}

// merged qkv + kr projection: grid.x = 288 + 96 = 384
__global__ __launch_bounds__(256) void gemm_qkvkr(const unsigned short* __restrict__ h_bf,
                                                  const unsigned short* __restrict__ wqkv,
                                                  const unsigned short* __restrict__ r2_bf,
                                                  const unsigned short* __restrict__ wr,
                                                  unsigned short* __restrict__ qkv_bf,
                                                  unsigned short* __restrict__ kr_bf) {
  int bx = blockIdx.x;
  const unsigned short *A, *W;
  unsigned short* C;
  int N, bm, bn;
  if (bx < 288) {
    A = h_bf; W = wqkv; C = qkv_bf; N = 2304;
    bm = (bx / 18) * 64; bn = (bx % 18) * 128;
  } else {
    int b2 = bx - 288;
    A = r2_bf; W = wr; C = kr_bf; N = 768;
    bm = (b2 / 6) * 64; bn = (b2 % 6) * 128;
  }
  gemm_tile<0, 1>(A, W, nullptr, nullptr, C, N, 768, bm, bn, 0, 768);
}

template <int ACT>
__global__ __launch_bounds__(256) void gemm_bias(const unsigned short* __restrict__ A,
                                                 const unsigned short* __restrict__ W,
                                                 const float* __restrict__ bias,
                                                 unsigned short* __restrict__ C,
                                                 int N, int K, int ncb) {
  int bx = blockIdx.x;
  gemm_tile<ACT, 1>(A, W, bias, nullptr, C, N, K, (bx / ncb) * 64, (bx % ncb) * 128, 0, K);
}

__global__ __launch_bounds__(256) void gemm_splitk(const unsigned short* __restrict__ A,
                                                   const unsigned short* __restrict__ W,
                                                   float* __restrict__ part,
                                                   int N, int K, int kch) {
  int kz = blockIdx.z;
  float* Cf = part + (size_t)kz * NTOK * N;
  gemm_tile<0, 0>(A, W, nullptr, Cf, nullptr, N, K,
                  blockIdx.y * 64, blockIdx.x * 128, kz * kch, (kz + 1) * kch);
}

// ============ MFMA fused attention, single pass online softmax ================
// Block: (64-row i-tile, b, n). 4 waves. Per 64-col j-tile:
//   stage K/KR -> score MFMAs (ac + 128-wide bd window) -> rel-shift via LDS ->
//   f32 scores in LDS -> per-row online max/exp -> bf16 P + V^T in LDS -> PV MFMA.
__global__ __launch_bounds__(256) void attn_kernel(const unsigned short* __restrict__ qkv,
                                                   const unsigned short* __restrict__ krb,
                                                   const int* __restrict__ seg_ids,
                                                   const int* __restrict__ input_mask,
                                                   const float* __restrict__ rwb,
                                                   const float* __restrict__ rrb,
                                                   const float* __restrict__ rsb,
                                                   const float* __restrict__ segemb,
                                                   unsigned short* __restrict__ vec_bf) {
  __shared__ __align__(16) char smem[64768];
  unsigned short* qw_s = (unsigned short*)(smem + 0);       // [64][72]
  unsigned short* qr_s = (unsigned short*)(smem + 9216);    // [64][72]
  unsigned short* k_s  = (unsigned short*)(smem + 18432);   // [64][72]
  unsigned short* kr_s = (unsigned short*)(smem + 27648);   // [128][72]
  unsigned short* bd_s = (unsigned short*)(smem + 46080);   // [64][136]
  float* sc_s  = (float*)(smem + 18432);                    // [64][68] f32, aliases k_s+kr_s
  unsigned short* pb_s = (unsigned short*)(smem + 46080);   // [64][64] xor, aliases bd_s
  unsigned short* vt_s = (unsigned short*)(smem + 54272);   // [64][64] xor, aliases bd_s
  float* efs    = (float*)(smem + 63488);                   // [2][64]
  float* frow_s = (float*)(smem + 64000);                   // [64]
  float* rinv_s = (float*)(smem + 64256);                   // [64]
  int*   segrow = (int*)(smem + 64512);                     // [64]

  const int it = blockIdx.x * 64, b = blockIdx.y, n = blockIdx.z;
  const int tid = threadIdx.x, lane = tid & 63, w = tid >> 6;

  // ---- setup: qw/qr (q + biases), ef table, segrow
  {
    int il = tid >> 2, d16 = (tid & 3) * 16;
    int t = (it + il) * B + b;
    short8v q0 = *(const short8v*)&qkv[(size_t)t * 2304 + n * 64 + d16];
    short8v q1 = *(const short8v*)&qkv[(size_t)t * 2304 + n * 64 + d16 + 8];
    short8v ow0, ow1, or0, or1;
#pragma unroll
    for (int e = 0; e < 8; ++e) {
      float f0 = b2f((unsigned short)q0[e]);
      float f1 = b2f((unsigned short)q1[e]);
      ow0[e] = (short)f2b(f0 + rwb[n * 64 + d16 + e]);
      ow1[e] = (short)f2b(f1 + rwb[n * 64 + d16 + 8 + e]);
      or0[e] = (short)f2b(f0 + rrb[n * 64 + d16 + e]);
      or1[e] = (short)f2b(f1 + rrb[n * 64 + d16 + 8 + e]);
    }
    *(short8v*)&qw_s[il * 72 + d16] = ow0;
    *(short8v*)&qw_s[il * 72 + d16 + 8] = ow1;
    *(short8v*)&qr_s[il * 72 + d16] = or0;
    *(short8v*)&qr_s[il * 72 + d16 + 8] = or1;
  }
  if (tid < 128) {
    int il = tid >> 1, s = tid & 1;
    int t = (it + il) * B + b;
    float acc = 0.0f;
    for (int d = 0; d < 64; ++d)
      acc = fmaf(b2f(qkv[(size_t)t * 2304 + n * 64 + d]) + rsb[n * 64 + d],
                 segemb[(s * H + n) * 64 + d], acc);
    efs[s * 64 + il] = acc;
  }
  if (tid < 64) segrow[tid] = seg_ids[(it + tid) * B + b];

  // stage tile 0 K/KR
  {
#pragma unroll
    for (int c = 0; c < 2; ++c) {
      int idx = tid + c * 256;
      int row = idx >> 3, k8 = (idx & 7) * 8;
      *(short8v*)&k_s[row * 72 + k8] =
          *(const short8v*)&qkv[(size_t)(row * B + b) * 2304 + 768 + n * 64 + k8];
    }
    int u0 = 448 - it;
#pragma unroll
    for (int c = 0; c < 4; ++c) {
      int idx = tid + c * 256;
      int row = idx >> 3, k8 = (idx & 7) * 8;
      *(short8v*)&kr_s[row * 72 + k8] =
          *(const short8v*)&krb[(size_t)(u0 + row) * 768 + n * 64 + k8];
    }
  }

  f32x4 acc_v[4];
#pragma unroll
  for (int mi = 0; mi < 4; ++mi) acc_v[mi] = (f32x4){0.f, 0.f, 0.f, 0.f};
  float m_run = -3.0e38f;   // per-thread: row tid>>2
  float rsq = 0.0f;         // partial row sum (cols (tid&3)*16.. per tile)
  const int srow = tid >> 2, sc0 = (tid & 3) * 16;

  __syncthreads();   // T1: tile-0 staging + setup ready

  for (int jt = 0; jt < 512; jt += 64) {
    // V loads for this tile, issued early (consumed in exp phase)
    const int vj = tid >> 2, vd16 = (tid & 3) * 16;
    short8v vl0 = *(const short8v*)&qkv[(size_t)((jt + vj) * B + b) * 2304 + 1536 + n * 64 + vd16];
    short8v vl1 = *(const short8v*)&qkv[(size_t)((jt + vj) * B + b) * 2304 + 1536 + n * 64 + vd16 + 8];

    // ---- score MFMAs
    f32x4 aac[4], abd[4][2];
#pragma unroll
    for (int mi = 0; mi < 4; ++mi) {
      aac[mi] = (f32x4){0.f, 0.f, 0.f, 0.f};
      abd[mi][0] = (f32x4){0.f, 0.f, 0.f, 0.f};
      abd[mi][1] = (f32x4){0.f, 0.f, 0.f, 0.f};
    }
#pragma unroll
    for (int ks = 0; ks < 2; ++ks) {
      int kb = ks * 32 + (lane >> 4) * 8;
      short8v aw[4], ar[4];
#pragma unroll
      for (int mi = 0; mi < 4; ++mi) {
        aw[mi] = *(const short8v*)&qw_s[(mi * 16 + (lane & 15)) * 72 + kb];
        ar[mi] = *(const short8v*)&qr_s[(mi * 16 + (lane & 15)) * 72 + kb];
      }
      short8v bk  = *(const short8v*)&k_s[(w * 16 + (lane & 15)) * 72 + kb];
      short8v br0 = *(const short8v*)&kr_s[(w * 32 + (lane & 15)) * 72 + kb];
      short8v br1 = *(const short8v*)&kr_s[(w * 32 + 16 + (lane & 15)) * 72 + kb];
#pragma unroll
      for (int mi = 0; mi < 4; ++mi) {
        aac[mi] = __builtin_amdgcn_mfma_f32_16x16x32_bf16(aw[mi], bk, aac[mi], 0, 0, 0);
        abd[mi][0] = __builtin_amdgcn_mfma_f32_16x16x32_bf16(ar[mi], br0, abd[mi][0], 0, 0, 0);
        abd[mi][1] = __builtin_amdgcn_mfma_f32_16x16x32_bf16(ar[mi], br1, abd[mi][1], 0, 0, 0);
      }
    }
    // bd window to LDS for rel-shift
#pragma unroll
    for (int mi = 0; mi < 4; ++mi)
#pragma unroll
      for (int ni = 0; ni < 2; ++ni)
#pragma unroll
        for (int r = 0; r < 4; ++r)
          bd_s[(mi * 16 + (lane >> 4) * 4 + r) * 136 + w * 32 + ni * 16 + (lane & 15)] =
              f2b(abd[mi][ni][r]);
    __syncthreads();   // T2

    // ---- combine -> f32 scores into sc_s (k_s/kr_s consumed, safe to alias)
    {
      int jl = w * 16 + (lane & 15);
      int jg = jt + jl;
      float maskterm = -1e30f * (float)input_mask[jg * B + b];
      int segj = seg_ids[jg * B + b];
#pragma unroll
      for (int mi = 0; mi < 4; ++mi)
#pragma unroll
        for (int r = 0; r < 4; ++r) {
          int il = mi * 16 + (lane >> 4) * 4 + r;
          float bd = b2f(bd_s[il * 136 + 64 - il + jl]);
          float e = efs[(segrow[il] != segj ? 1 : 0) * 64 + il];
          sc_s[il * 68 + jl] = (aac[mi][r] + bd + e) * 0.125f + maskterm;
        }
    }
    __syncthreads();   // T3

    // ---- online max + exp + P write (+ V^T write, frow)
    {
      float4 f0 = *(const float4*)&sc_s[srow * 68 + sc0];
      float4 f1 = *(const float4*)&sc_s[srow * 68 + sc0 + 4];
      float4 f2 = *(const float4*)&sc_s[srow * 68 + sc0 + 8];
      float4 f3 = *(const float4*)&sc_s[srow * 68 + sc0 + 12];
      float mx = fmaxf(fmaxf(fmaxf(f0.x, f0.y), fmaxf(f0.z, f0.w)),
                       fmaxf(fmaxf(f1.x, f1.y), fmaxf(f1.z, f1.w)));
      mx = fmaxf(mx, fmaxf(fmaxf(fmaxf(f2.x, f2.y), fmaxf(f2.z, f2.w)),
                           fmaxf(fmaxf(f3.x, f3.y), fmaxf(f3.z, f3.w))));
      mx = fmaxf(mx, __shfl_xor(mx, 1, 4));
      mx = fmaxf(mx, __shfl_xor(mx, 2, 4));
      float mnew = fmaxf(m_run, mx);
      float fsc = __expf(m_run - mnew);
      m_run = mnew;
      float p0 = __expf(f0.x - mnew), p1 = __expf(f0.y - mnew);
      float p2 = __expf(f0.z - mnew), p3 = __expf(f0.w - mnew);
      float p4 = __expf(f1.x - mnew), p5 = __expf(f1.y - mnew);
      float p6 = __expf(f1.z - mnew), p7 = __expf(f1.w - mnew);
      float p8 = __expf(f2.x - mnew), p9 = __expf(f2.y - mnew);
      float pa = __expf(f2.z - mnew), pb = __expf(f2.w - mnew);
      float pc = __expf(f3.x - mnew), pd = __expf(f3.y - mnew);
      float pe = __expf(f3.z - mnew), pf = __expf(f3.w - mnew);
      rsq = rsq * fsc + ((p0 + p1 + p2 + p3) + (p4 + p5 + p6 + p7)) +
                        ((p8 + p9 + pa + pb) + (pc + pd + pe + pf));
      short8v o0, o1;
      o0[0] = (short)f2b(p0); o0[1] = (short)f2b(p1); o0[2] = (short)f2b(p2); o0[3] = (short)f2b(p3);
      o0[4] = (short)f2b(p4); o0[5] = (short)f2b(p5); o0[6] = (short)f2b(p6); o0[7] = (short)f2b(p7);
      o1[0] = (short)f2b(p8); o1[1] = (short)f2b(p9); o1[2] = (short)f2b(pa); o1[3] = (short)f2b(pb);
      o1[4] = (short)f2b(pc); o1[5] = (short)f2b(pd); o1[6] = (short)f2b(pe); o1[7] = (short)f2b(pf);
      int key = vkey(srow);
      *(short8v*)&pb_s[srow * 64 + (sc0 ^ key)] = o0;
      *(short8v*)&pb_s[srow * 64 + ((sc0 + 8) ^ key)] = o1;
      if ((tid & 3) == 0) frow_s[srow] = fsc;
      // V^T write (vl0/vl1 loaded at tile top)
#pragma unroll
      for (int e = 0; e < 8; ++e) {
        int d0 = vd16 + e, d1 = vd16 + 8 + e;
        vt_s[d0 * 64 + (vj ^ vkey(d0))] = (unsigned short)vl0[e];
        vt_s[d1 * 64 + (vj ^ vkey(d1))] = (unsigned short)vl1[e];
      }
    }
    __syncthreads();   // T4

    // ---- rescale O by frow, PV MFMAs, and stage next tile's K/KR
#pragma unroll
    for (int mi = 0; mi < 4; ++mi) {
#pragma unroll
      for (int r = 0; r < 4; ++r)
        acc_v[mi][r] *= frow_s[mi * 16 + (lane >> 4) * 4 + r];
    }
#pragma unroll
    for (int ks = 0; ks < 2; ++ks) {
      int kb = ks * 32 + (lane >> 4) * 8;
      int vrow = w * 16 + (lane & 15);
      short8v bv = *(const short8v*)&vt_s[vrow * 64 + (kb ^ vkey(vrow))];
#pragma unroll
      for (int mi = 0; mi < 4; ++mi) {
        int prow = mi * 16 + (lane & 15);
        short8v ap = *(const short8v*)&pb_s[prow * 64 + (kb ^ vkey(prow))];
        acc_v[mi] = __builtin_amdgcn_mfma_f32_16x16x32_bf16(ap, bv, acc_v[mi], 0, 0, 0);
      }
    }
    if (jt < 448) {
      int jn = jt + 64;
#pragma unroll
      for (int c = 0; c < 2; ++c) {
        int idx = tid + c * 256;
        int row = idx >> 3, k8 = (idx & 7) * 8;
        *(short8v*)&k_s[row * 72 + k8] =
            *(const short8v*)&qkv[(size_t)((jn + row) * B + b) * 2304 + 768 + n * 64 + k8];
      }
      int u0 = 448 - it + jn;
#pragma unroll
      for (int c = 0; c < 4; ++c) {
        int idx = tid + c * 256;
        int row = idx >> 3, k8 = (idx & 7) * 8;
        *(short8v*)&kr_s[row * 72 + k8] =
            *(const short8v*)&krb[(size_t)(u0 + row) * 768 + n * 64 + k8];
      }
    }
    __syncthreads();   // T1 (next)
  }

  // ---- final row sums -> rinv
  {
    float tot = rsq;
    tot += __shfl_xor(tot, 1, 4);
    tot += __shfl_xor(tot, 2, 4);
    if ((tid & 3) == 0) rinv_s[srow] = 1.0f / tot;
  }
  __syncthreads();

  // ---- epilogue
#pragma unroll
  for (int mi = 0; mi < 4; ++mi)
#pragma unroll
    for (int r = 0; r < 4; ++r) {
      int row = mi * 16 + (lane >> 4) * 4 + r;
      int d = w * 16 + (lane & 15);
      int t = (it + row) * B + b;
      vec_bf[(size_t)t * D + n * 64 + d] = f2b(acc_v[mi][r] * rinv_s[row]);
    }
}

// ------- fused split-K reduce + bias + residual + layernorm -> h, h_bf --------
template <int P, int HASBIAS>
__global__ __launch_bounds__(256) void add_ln_reduce(const float* __restrict__ part,
                                                     const float* __restrict__ bias,
                                                     float* __restrict__ h,
                                                     unsigned short* __restrict__ h_bf,
                                                     const float* __restrict__ g,
                                                     const float* __restrict__ bi) {
  int t = blockIdx.x;
  int tid = threadIdx.x;
  __shared__ float red[256];
  float v[3];
  float s = 0.0f;
#pragma unroll
  for (int j = 0; j < 3; ++j) {
    int c = tid + j * 256;
    float x = 0.0f;
#pragma unroll
    for (int p = 0; p < P; ++p)
      x += part[(size_t)p * NTOK * D + (size_t)t * D + c];
    if (HASBIAS) x += bias[c];
    v[j] = x + h[(size_t)t * D + c];
    s += v[j];
  }
  red[tid] = s;
  __syncthreads();
  for (int st = 128; st > 0; st >>= 1) {
    if (tid < st) red[tid] += red[tid + st];
    __syncthreads();
  }
  float mu = red[0] / (float)D;
  __syncthreads();
  float s2 = 0.0f;
#pragma unroll
  for (int j = 0; j < 3; ++j) {
    float dd = v[j] - mu;
    s2 += dd * dd;
  }
  red[tid] = s2;
  __syncthreads();
  for (int st = 128; st > 0; st >>= 1) {
    if (tid < st) red[tid] += red[tid + st];
    __syncthreads();
  }
  float var = red[0] / (float)D;
  float rstd = rsqrtf(var + 1e-3f);
  __syncthreads();
#pragma unroll
  for (int j = 0; j < 3; ++j) {
    int c = tid + j * 256;
    float o = (v[j] - mu) * rstd * g[c] + bi[c];
    h[(size_t)t * D + c] = o;
    h_bf[(size_t)t * D + c] = f2b(o);
  }
}

extern "C" void kernel_launch(void* const* d_in, const int* in_sizes, int n_in,
                              void* d_out, int out_size, void* d_ws, size_t ws_size,
                              hipStream_t stream) {
  const int*   inp_k      = (const int*)d_in[0];
  const int*   seg_ids    = (const int*)d_in[1];
  const int*   input_mask = (const int*)d_in[2];
  const float* lut        = (const float*)d_in[3];
  const float* Wq         = (const float*)d_in[4];
  const float* Wk         = (const float*)d_in[5];
  const float* Wv         = (const float*)d_in[6];
  const float* Wr         = (const float*)d_in[7];
  const float* Wo         = (const float*)d_in[8];
  const float* r_w_bias   = (const float*)d_in[9];
  const float* r_r_bias   = (const float*)d_in[10];
  const float* r_s_bias   = (const float*)d_in[11];
  const float* seg_embed  = (const float*)d_in[12];
  const float* ln_attn_g  = (const float*)d_in[13];
  const float* ln_attn_b  = (const float*)d_in[14];
  const float* ln_ff_g    = (const float*)d_in[15];
  const float* ln_ff_b    = (const float*)d_in[16];
  const float* ff_w1      = (const float*)d_in[17];
  const float* ff_b1      = (const float*)d_in[18];
  const float* ff_w2      = (const float*)d_in[19];
  const float* ff_b2      = (const float*)d_in[20];

  float* h = (float*)d_out;
  char* wp = (char*)d_ws;
  auto alloc = [&](size_t bytes) -> void* {
    void* p = (void*)wp;
    wp += (bytes + 255) & ~(size_t)255;
    return p;
  };
  const size_t TOKD = (size_t)NTOK * D;
  const size_t DD = (size_t)D * D;
  const size_t DDI = (size_t)D * DI;
  unsigned short* qkv_bf = (unsigned short*)alloc((size_t)NTOK * 2304 * 2);
  unsigned short* kr_bf  = (unsigned short*)alloc(TOKD * 2);
  unsigned short* h_bf   = (unsigned short*)alloc(TOKD * 2);
  unsigned short* r2_bf  = (unsigned short*)alloc(TOKD * 2);
  unsigned short* vec_bf = (unsigned short*)alloc(TOKD * 2);
  unsigned short* ff1_bf = (unsigned short*)alloc((size_t)NTOK * DI * 2);
  float* part = (float*)alloc((size_t)4 * TOKD * 4);
  unsigned short* wqkv_t = (unsigned short*)alloc((size_t)NL * 3 * DD * 2);
  unsigned short* wr_t   = (unsigned short*)alloc((size_t)NL * DD * 2);
  unsigned short* wo_t   = (unsigned short*)alloc((size_t)NL * DD * 2);
  unsigned short* w1_t   = (unsigned short*)alloc((size_t)NL * DDI * 2);
  unsigned short* w2_t   = (unsigned short*)alloc((size_t)NL * DDI * 2);

  prep_all<<<NL * 1872, 256, 0, stream>>>(Wq, Wk, Wv, Wr, Wo, ff_w1, ff_w2,
                                          wqkv_t, wr_t, wo_t, w1_t, w2_t);
  embed_kernel<<<NTOK, 256, 0, stream>>>(inp_k, lut, h, h_bf);
  posemb_kernel<<<2 * S, 384, 0, stream>>>(r2_bf);

  for (int l = 0; l < NL; ++l) {
    gemm_qkvkr<<<384, 256, 0, stream>>>(h_bf, wqkv_t + (size_t)l * 3 * DD,
                                        r2_bf, wr_t + (size_t)l * DD,
                                        qkv_bf, kr_bf);

    attn_kernel<<<dim3(8, B, H), 256, 0, stream>>>(
        qkv_bf, kr_bf, seg_ids, input_mask,
        r_w_bias + (size_t)l * D, r_r_bias + (size_t)l * D,
        r_s_bias + (size_t)l * D, seg_embed + (size_t)l * 2 * H * DH,
        vec_bf);

    gemm_splitk<<<dim3(6, 16, 2), 256, 0, stream>>>(
        vec_bf, wo_t + (size_t)l * DD, part, D, D, 384);
    add_ln_reduce<2, 0><<<NTOK, 256, 0, stream>>>(
        part, nullptr, h, h_bf, ln_attn_g + (size_t)l * D, ln_attn_b + (size_t)l * D);

    gemm_bias<1><<<24 * 16, 256, 0, stream>>>(
        h_bf, w1_t + (size_t)l * DDI, ff_b1 + (size_t)l * DI, ff1_bf, DI, D, 24);

    gemm_splitk<<<dim3(6, 16, 4), 256, 0, stream>>>(
        ff1_bf, w2_t + (size_t)l * DDI, part, D, DI, 768);
    add_ln_reduce<4, 1><<<NTOK, 256, 0, stream>>>(
        part, ff_b2 + (size_t)l * D, h, h_bf, ln_ff_g + (size_t)l * D, ln_ff_b + (size_t)l * D);
  }
}

// Round 7
// 1299.949 us; speedup vs baseline: 11.8236x; 1.0179x over previous
//
#include <hip/hip_runtime.h>
#include <hip/hip_bf16.h>
#include <math.h>

#define S 512
#define B 2
#define D 768
#define H 12
#define DH 64
#define DI 3072
#define NL 12
#define NTOK (S * B)   // 1024

typedef __attribute__((ext_vector_type(8))) short short8v;
typedef __attribute__((ext_vector_type(4))) float f32x4;

__device__ __forceinline__ unsigned short f2b(float f) {
  union { float f; unsigned int u; } v; v.f = f;
  unsigned int r = v.u + 0x7fffu + ((v.u >> 16) & 1u);
  return (unsigned short)(r >> 16);
}
__device__ __forceinline__ float b2f(unsigned short u) {
  union { unsigned int u; float f; } v; v.u = ((unsigned int)u) << 16;
  return v.f;
}

__device__ __forceinline__ float gelu_f(float x) {
  const float c = 0.7978845608028654f;  // sqrt(2/pi)
  float t = tanhf(c * (x + 0.044715f * x * x * x));
  return x * 0.5f * (1.0f + t);
}

// xor swizzle key for bf16 LDS tiles with 64-ushort rows (8-ushort granular)
__device__ __forceinline__ int vkey(int r) {
  return ((((r & 7) ^ ((r >> 3) & 7)) & 7) << 3);
}

// ---------------- embedding gather ----------------
__global__ __launch_bounds__(256) void embed_kernel(const int* __restrict__ inp_k,
                                                    const float* __restrict__ lut,
                                                    float* __restrict__ h,
                                                    unsigned short* __restrict__ h_bf) {
  int t = blockIdx.x;
  int id = inp_k[t];
  for (int j = threadIdx.x; j < D; j += 256) {
    float v = lut[(size_t)id * D + j];
    h[t * D + j] = v;
    h_bf[t * D + j] = f2b(v);
  }
}

// ---------------- positional embedding -> bf16 [2S, D] ----------------
__global__ __launch_bounds__(384) void posemb_kernel(unsigned short* __restrict__ r2b) {
  int j = blockIdx.x;
  int d = threadIdx.x;
  float pos = (float)(S - j);
  float inv_freq = expf(-logf(10000.0f) * (2.0f * (float)d / (float)D));
  float x = pos * inv_freq;
  r2b[j * D + d]       = f2b(sinf(x));
  r2b[j * D + 384 + d] = f2b(cosf(x));
}

// ======================= weight prep (unchanged) ==============================
__device__ __forceinline__ void transpose_swz(const float* __restrict__ src,   // [K][N] row-major
                                              unsigned short* __restrict__ dst,
                                              int K, int N, int tile, int n_base,
                                              unsigned short* __restrict__ Ls /*[64*72]*/) {
  int ntk = K >> 6;
  int tk = tile % ntk, tn = tile / ntk;
  int k0 = tk << 6, n0 = tn << 6;
  int tid = threadIdx.x;
  int kk = tid >> 4, c4 = (tid & 15) * 4;
#pragma unroll
  for (int r = 0; r < 4; ++r) {
    int k = kk + r * 16;
    float4 a = *(const float4*)&src[(size_t)(k0 + k) * N + n0 + c4];
    Ls[(c4 + 0) * 72 + k] = f2b(a.x);
    Ls[(c4 + 1) * 72 + k] = f2b(a.y);
    Ls[(c4 + 2) * 72 + k] = f2b(a.z);
    Ls[(c4 + 3) * 72 + k] = f2b(a.w);
  }
  __syncthreads();
  int nl = tid >> 2, kc0 = (tid & 3) << 4;
  int ng = n_base + n0;
  size_t tilebase = ((size_t)(ng >> 7) * ntk + tk) * 8192;
  int row = (ng & 64) + nl;
  int key = (row & 7) << 3;
  short8v v0 = *(short8v*)&Ls[nl * 72 + kc0];
  short8v v1 = *(short8v*)&Ls[nl * 72 + kc0 + 8];
  *(short8v*)&dst[tilebase + row * 64 + (kc0 ^ key)] = v0;
  *(short8v*)&dst[tilebase + row * 64 + ((kc0 + 8) ^ key)] = v1;
}

// per layer: 432 qkv + 144 wr + 576 w1 + 576 w2 + 144 wo = 1872 blocks
__global__ __launch_bounds__(256) void prep_all(const float* __restrict__ Wq,
                                                const float* __restrict__ Wk,
                                                const float* __restrict__ Wv,
                                                const float* __restrict__ Wr,
                                                const float* __restrict__ Wo,
                                                const float* __restrict__ W1,
                                                const float* __restrict__ W2,
                                                unsigned short* __restrict__ wqkv_t,
                                                unsigned short* __restrict__ wr_t,
                                                unsigned short* __restrict__ wo_t,
                                                unsigned short* __restrict__ w1_t,
                                                unsigned short* __restrict__ w2_t) {
  __shared__ __align__(16) unsigned short Ls[64 * 72];
  const size_t DD = (size_t)D * D;
  const size_t DDI = (size_t)D * DI;
  int tb = blockIdx.x;
  int l = tb / 1872, t2 = tb % 1872;
  int tid = threadIdx.x;
  if (t2 < 432) {
    int which = t2 / 144, tile = t2 % 144;
    const float* src = (which == 0 ? Wq : (which == 1 ? Wk : Wv)) + l * DD;
    transpose_swz(src, wqkv_t + l * 3 * DD, D, D, tile, which * D, Ls);
  } else if (t2 < 576) {
    transpose_swz(Wr + l * DD, wr_t + l * DD, D, D, t2 - 432, 0, Ls);
  } else if (t2 < 1152) {
    transpose_swz(W1 + l * DDI, w1_t + l * DDI, D, DI, t2 - 576, 0, Ls);
  } else if (t2 < 1728) {
    transpose_swz(W2 + l * DDI, w2_t + l * DDI, DI, D, t2 - 1152, 0, Ls);
  } else {
    // Wo: already [N][K]; swizzle-copy, no LDS
    int c = t2 - 1728;
    int tkk = c % 12, tnn = c / 12;
    int k0 = tkk << 6, n0 = tnn << 6;
    int nl = tid >> 2, kc0 = (tid & 3) << 4;
    const float* srcp = Wo + l * DD + (size_t)(n0 + nl) * D + k0 + kc0;
    float4 a0 = *(const float4*)&srcp[0];
    float4 a1 = *(const float4*)&srcp[4];
    float4 a2 = *(const float4*)&srcp[8];
    float4 a3 = *(const float4*)&srcp[12];
    short8v v0, v1;
    v0[0] = (short)f2b(a0.x); v0[1] = (short)f2b(a0.y); v0[2] = (short)f2b(a0.z); v0[3] = (short)f2b(a0.w);
    v0[4] = (short)f2b(a1.x); v0[5] = (short)f2b(a1.y); v0[6] = (short)f2b(a1.z); v0[7] = (short)f2b(a1.w);
    v1[0] = (short)f2b(a2.x); v1[1] = (short)f2b(a2.y); v1[2] = (short)f2b(a2.z); v1[3] = (short)f2b(a2.w);
    v1[4] = (short)f2b(a3.x); v1[5] = (short)f2b(a3.y); v1[6] = (short)f2b(a3.z); v1[7] = (short)f2b(a3.w);
    unsigned short* dst = wo_t + l * DD;
    size_t tilebase = ((size_t)(n0 >> 7) * 12 + tkk) * 8192;
    int row = (n0 & 64) + nl;
    int key = (row & 7) << 3;
    *(short8v*)&dst[tilebase + row * 64 + (kc0 ^ key)] = v0;
    *(short8v*)&dst[tilebase + row * 64 + ((kc0 + 8) ^ key)] = v1;
  }
}

// ======================= MFMA GEMM (global_load_lds + swizzle, unchanged) =====
template <int ACT, int OUTBF>
__device__ __forceinline__ void gemm_tile(const unsigned short* __restrict__ A,
                                          const unsigned short* __restrict__ Wt,
                                          const float* __restrict__ bias,
                                          float* __restrict__ Cf,
                                          unsigned short* __restrict__ Cb,
                                          int N, int K, int bm, int bn,
                                          int kbeg, int kend) {
  __shared__ __align__(16) unsigned short As[64 * 64];
  __shared__ __align__(16) unsigned short Bs[128 * 64];
  const int tid = threadIdx.x, lane = tid & 63, w = tid >> 6;
  const int l8 = lane >> 3, lm8 = lane & 7;
  const int aColByte = ((lm8 ^ l8) << 4);
  const int KT = K >> 6;
  const size_t wtn = (size_t)(bn >> 7) * KT;

  f32x4 acc[4][2];
#pragma unroll
  for (int mi = 0; mi < 4; ++mi)
#pragma unroll
    for (int ni = 0; ni < 2; ++ni)
      acc[mi][ni] = (f32x4){0.f, 0.f, 0.f, 0.f};

  for (int kt = kbeg; kt < kend; kt += 64) {
    __syncthreads();
#pragma unroll
    for (int c = 0; c < 2; ++c) {
      int row = c * 32 + w * 8 + l8;
      const char* src = (const char*)&A[(size_t)(bm + row) * K + kt] + aColByte;
      __builtin_amdgcn_global_load_lds(
          (const __attribute__((address_space(1))) void*)src,
          (__attribute__((address_space(3))) void*)((char*)As + c * 4096 + w * 1024),
          16, 0, 0);
    }
    const char* wt = (const char*)&Wt[(wtn + (kt >> 6)) * 8192];
#pragma unroll
    for (int c = 0; c < 4; ++c) {
      __builtin_amdgcn_global_load_lds(
          (const __attribute__((address_space(1))) void*)(wt + c * 4096 + w * 1024 + lane * 16),
          (__attribute__((address_space(3))) void*)((char*)Bs + c * 4096 + w * 1024),
          16, 0, 0);
    }
    __syncthreads();
#pragma unroll
    for (int ks = 0; ks < 2; ++ks) {
      const int kus = ks * 32 + (lane >> 4) * 8;
      short8v af[4], bf[2];
#pragma unroll
      for (int mi = 0; mi < 4; ++mi) {
        int row = mi * 16 + (lane & 15);
        af[mi] = *(const short8v*)&As[row * 64 + (kus ^ ((row & 7) << 3))];
      }
#pragma unroll
      for (int ni = 0; ni < 2; ++ni) {
        int row = w * 32 + ni * 16 + (lane & 15);
        bf[ni] = *(const short8v*)&Bs[row * 64 + (kus ^ ((row & 7) << 3))];
      }
#pragma unroll
      for (int mi = 0; mi < 4; ++mi)
#pragma unroll
        for (int ni = 0; ni < 2; ++ni)
          acc[mi][ni] = __builtin_amdgcn_mfma_f32_16x16x32_bf16(af[mi], bf[ni], acc[mi][ni], 0, 0, 0);
    }
  }

  int r0 = (lane >> 4) * 4, cc = lane & 15;
#pragma unroll
  for (int mi = 0; mi < 4; ++mi) {
    int row = bm + mi * 16 + r0;
#pragma unroll
    for (int ni = 0; ni < 2; ++ni) {
      int col = bn + w * 32 + ni * 16 + cc;
      float bv = bias ? bias[col] : 0.0f;
#pragma unroll
      for (int r = 0; r < 4; ++r) {
        float v = acc[mi][ni][r] + bv;
        if (ACT == 1) v = gelu_f(v);
        if (OUTBF) Cb[(size_t)(row + r) * N + col] = f2b(v);
        else       Cf[(size_t)(row + r) * N + col] = v;
      }
    }
  }
}

// qkv projection only: grid.x = 288
__global__ __launch_bounds__(256) void gemm_qkv(const unsigned short* __restrict__ h_bf,
                                                const unsigned short* __restrict__ wqkv,
                                                unsigned short* __restrict__ qkv_bf) {
  int bx = blockIdx.x;
  gemm_tile<0, 1>(h_bf, wqkv, nullptr, nullptr, qkv_bf, 2304, 768,
                  (bx / 18) * 64, (bx % 18) * 128, 0, 768);
}

// kr projections for ALL layers upfront: grid.x = 12 * 96 = 1152
__global__ __launch_bounds__(256) void gemm_kr_all(const unsigned short* __restrict__ r2_bf,
                                                   const unsigned short* __restrict__ wr_t,
                                                   unsigned short* __restrict__ kr_all) {
  int bx = blockIdx.x;
  int l = bx / 96, b2 = bx % 96;
  gemm_tile<0, 1>(r2_bf, wr_t + (size_t)l * D * D, nullptr, nullptr,
                  kr_all + (size_t)l * NTOK * D, 768, 768,
                  (b2 / 6) * 64, (b2 % 6) * 128, 0, 768);
}

template <int ACT>
__global__ __launch_bounds__(256) void gemm_bias(const unsigned short* __restrict__ A,
                                                 const unsigned short* __restrict__ W,
                                                 const float* __restrict__ bias,
                                                 unsigned short* __restrict__ C,
                                                 int N, int K, int ncb) {
  int bx = blockIdx.x;
  gemm_tile<ACT, 1>(A, W, bias, nullptr, C, N, K, (bx / ncb) * 64, (bx % ncb) * 128, 0, K);
}

__global__ __launch_bounds__(256) void gemm_splitk(const unsigned short* __restrict__ A,
                                                   const unsigned short* __restrict__ W,
                                                   float* __restrict__ part,
                                                   int N, int K, int kch) {
  int kz = blockIdx.z;
  float* Cf = part + (size_t)kz * NTOK * N;
  gemm_tile<0, 0>(A, W, nullptr, Cf, nullptr, N, K,
                  blockIdx.y * 64, blockIdx.x * 128, kz * kch, (kz + 1) * kch);
}

// ============ MFMA fused attention, 32-row i-tile, online softmax =============
// Block: (32-row i-tile, b, n) = 384 blocks. 4 waves. bd window = 96 kr rows.
// Score jobs: 10 col-frags (4 ac + 6 bd) over 4 waves as {w}, {w+4}, {w+8 if <10}.
__global__ __launch_bounds__(256) void attn_kernel(const unsigned short* __restrict__ qkv,
                                                   const unsigned short* __restrict__ krb,
                                                   const int* __restrict__ seg_ids,
                                                   const int* __restrict__ input_mask,
                                                   const float* __restrict__ rwb,
                                                   const float* __restrict__ rrb,
                                                   const float* __restrict__ rsb,
                                                   const float* __restrict__ segemb,
                                                   unsigned short* __restrict__ vec_bf) {
  __shared__ __align__(16) char smem[51840];
  unsigned short* qw_s = (unsigned short*)(smem + 0);       // [32][72]
  unsigned short* qr_s = (unsigned short*)(smem + 4608);    // [32][72]
  unsigned short* k_s  = (unsigned short*)(smem + 9216);    // [64][72]
  unsigned short* kr_s = (unsigned short*)(smem + 18432);   // [96][72]
  unsigned short* bd_s = (unsigned short*)(smem + 32256);   // [32][104]
  unsigned short* vt_s = (unsigned short*)(smem + 38912);   // [64][64] xor
  unsigned short* pb_s = (unsigned short*)(smem + 47104);   // [32][64] xor
  float* sc_s  = (float*)(smem + 9216);                     // [32][68] f32, aliases k_s
  float* efs    = (float*)(smem + 51200);                   // [2][32]
  float* frow_s = (float*)(smem + 51456);                   // [32]
  float* rinv_s = (float*)(smem + 51584);                   // [32]
  int*   segrow = (int*)(smem + 51712);                     // [32]

  const int it = blockIdx.x * 32, b = blockIdx.y, n = blockIdx.z;
  const int tid = threadIdx.x, lane = tid & 63, w = tid >> 6;

  // ---- setup: qw/qr (q + biases), ef table, segrow
  {
    int il = tid >> 3, d8 = (tid & 7) * 8;
    int t = (it + il) * B + b;
    short8v q0 = *(const short8v*)&qkv[(size_t)t * 2304 + n * 64 + d8];
    short8v ow0, or0;
#pragma unroll
    for (int e = 0; e < 8; ++e) {
      float f0 = b2f((unsigned short)q0[e]);
      ow0[e] = (short)f2b(f0 + rwb[n * 64 + d8 + e]);
      or0[e] = (short)f2b(f0 + rrb[n * 64 + d8 + e]);
    }
    *(short8v*)&qw_s[il * 72 + d8] = ow0;
    *(short8v*)&qr_s[il * 72 + d8] = or0;
  }
  if (tid < 64) {
    int il = tid >> 1, s = tid & 1;
    int t = (it + il) * B + b;
    float acc = 0.0f;
    for (int d = 0; d < 64; ++d)
      acc = fmaf(b2f(qkv[(size_t)t * 2304 + n * 64 + d]) + rsb[n * 64 + d],
                 segemb[(s * H + n) * 64 + d], acc);
    efs[s * 32 + il] = acc;
  }
  if (tid < 32) segrow[tid] = seg_ids[(it + tid) * B + b];

  // stage tile 0 K (64 rows) / KR (96 rows)
  {
#pragma unroll
    for (int c = 0; c < 2; ++c) {
      int idx = tid + c * 256;
      int row = idx >> 3, k8 = (idx & 7) * 8;
      *(short8v*)&k_s[row * 72 + k8] =
          *(const short8v*)&qkv[(size_t)(row * B + b) * 2304 + 768 + n * 64 + k8];
    }
    int u0 = 481 - it;
#pragma unroll
    for (int c = 0; c < 3; ++c) {
      int idx = tid + c * 256;
      int row = idx >> 3, k8 = (idx & 7) * 8;
      *(short8v*)&kr_s[row * 72 + k8] =
          *(const short8v*)&krb[(size_t)(u0 + row) * 768 + n * 64 + k8];
    }
  }

  f32x4 acc_v[2];
  acc_v[0] = (f32x4){0.f, 0.f, 0.f, 0.f};
  acc_v[1] = (f32x4){0.f, 0.f, 0.f, 0.f};
  float m_run = -3.0e38f;   // per-thread: row tid>>3
  float rsq = 0.0f;
  const int srow = tid >> 3, sc0 = (tid & 7) * 8;

  __syncthreads();   // T1: tile-0 staging + setup ready

  for (int jt = 0; jt < 512; jt += 64) {
    // V loads for this tile, issued early (consumed in exp phase)
    const int vj = tid >> 2, vd16 = (tid & 3) * 16;
    short8v vl0 = *(const short8v*)&qkv[(size_t)((jt + vj) * B + b) * 2304 + 1536 + n * 64 + vd16];
    short8v vl1 = *(const short8v*)&qkv[(size_t)((jt + vj) * B + b) * 2304 + 1536 + n * 64 + vd16 + 8];

    // ---- score MFMAs: jobs t=0 (ac col w), t=1 (bd col w), t=2 (bd col w+4, w<2)
    f32x4 jacc[3][2];
#pragma unroll
    for (int t = 0; t < 3; ++t) {
      jacc[t][0] = (f32x4){0.f, 0.f, 0.f, 0.f};
      jacc[t][1] = (f32x4){0.f, 0.f, 0.f, 0.f};
    }
#pragma unroll
    for (int ks = 0; ks < 2; ++ks) {
      int kb = ks * 32 + (lane >> 4) * 8;
      short8v aw[2], ar[2];
#pragma unroll
      for (int mi = 0; mi < 2; ++mi) {
        aw[mi] = *(const short8v*)&qw_s[(mi * 16 + (lane & 15)) * 72 + kb];
        ar[mi] = *(const short8v*)&qr_s[(mi * 16 + (lane & 15)) * 72 + kb];
      }
      // t=0: ac
      {
        short8v bk = *(const short8v*)&k_s[(w * 16 + (lane & 15)) * 72 + kb];
        jacc[0][0] = __builtin_amdgcn_mfma_f32_16x16x32_bf16(aw[0], bk, jacc[0][0], 0, 0, 0);
        jacc[0][1] = __builtin_amdgcn_mfma_f32_16x16x32_bf16(aw[1], bk, jacc[0][1], 0, 0, 0);
      }
      // t=1: bd col-frag w
      {
        short8v br = *(const short8v*)&kr_s[(w * 16 + (lane & 15)) * 72 + kb];
        jacc[1][0] = __builtin_amdgcn_mfma_f32_16x16x32_bf16(ar[0], br, jacc[1][0], 0, 0, 0);
        jacc[1][1] = __builtin_amdgcn_mfma_f32_16x16x32_bf16(ar[1], br, jacc[1][1], 0, 0, 0);
      }
      // t=2: bd col-frag w+4 (only waves 0,1)
      if (w < 2) {
        short8v br = *(const short8v*)&kr_s[((w + 4) * 16 + (lane & 15)) * 72 + kb];
        jacc[2][0] = __builtin_amdgcn_mfma_f32_16x16x32_bf16(ar[0], br, jacc[2][0], 0, 0, 0);
        jacc[2][1] = __builtin_amdgcn_mfma_f32_16x16x32_bf16(ar[1], br, jacc[2][1], 0, 0, 0);
      }
    }
    // bd frags -> bd_s (cols cf*16 + lane&15)
#pragma unroll
    for (int t = 1; t < 3; ++t) {
      int cf = w + (t - 1) * 4;
      if (t == 1 || w < 2) {
#pragma unroll
        for (int mi = 0; mi < 2; ++mi)
#pragma unroll
          for (int r = 0; r < 4; ++r)
            bd_s[(mi * 16 + (lane >> 4) * 4 + r) * 104 + cf * 16 + (lane & 15)] =
                f2b(jacc[t][mi][r]);
      }
    }
    __syncthreads();   // T2

    // ---- combine -> f32 scores into sc_s (aliases k_s; K consumed)
    {
      int jl = w * 16 + (lane & 15);
      int jg = jt + jl;
      float maskterm = -1e30f * (float)input_mask[jg * B + b];
      int segj = seg_ids[jg * B + b];
#pragma unroll
      for (int mi = 0; mi < 2; ++mi)
#pragma unroll
        for (int r = 0; r < 4; ++r) {
          int il = mi * 16 + (lane >> 4) * 4 + r;
          float bd = b2f(bd_s[il * 104 + 31 - il + jl]);
          float e = efs[(segrow[il] != segj ? 1 : 0) * 32 + il];
          sc_s[il * 68 + jl] = (jacc[0][mi][r] + bd + e) * 0.125f + maskterm;
        }
    }
    __syncthreads();   // T3

    // ---- online max + exp + P write (+ V^T write, frow)
    {
      float4 f0 = *(const float4*)&sc_s[srow * 68 + sc0];
      float4 f1 = *(const float4*)&sc_s[srow * 68 + sc0 + 4];
      float mx = fmaxf(fmaxf(fmaxf(f0.x, f0.y), fmaxf(f0.z, f0.w)),
                       fmaxf(fmaxf(f1.x, f1.y), fmaxf(f1.z, f1.w)));
      mx = fmaxf(mx, __shfl_xor(mx, 1, 8));
      mx = fmaxf(mx, __shfl_xor(mx, 2, 8));
      mx = fmaxf(mx, __shfl_xor(mx, 4, 8));
      float mnew = fmaxf(m_run, mx);
      float fsc = __expf(m_run - mnew);
      m_run = mnew;
      float p0 = __expf(f0.x - mnew), p1 = __expf(f0.y - mnew);
      float p2 = __expf(f0.z - mnew), p3 = __expf(f0.w - mnew);
      float p4 = __expf(f1.x - mnew), p5 = __expf(f1.y - mnew);
      float p6 = __expf(f1.z - mnew), p7 = __expf(f1.w - mnew);
      rsq = rsq * fsc + ((p0 + p1 + p2 + p3) + (p4 + p5 + p6 + p7));
      short8v o0;
      o0[0] = (short)f2b(p0); o0[1] = (short)f2b(p1); o0[2] = (short)f2b(p2); o0[3] = (short)f2b(p3);
      o0[4] = (short)f2b(p4); o0[5] = (short)f2b(p5); o0[6] = (short)f2b(p6); o0[7] = (short)f2b(p7);
      *(short8v*)&pb_s[srow * 64 + (sc0 ^ vkey(srow))] = o0;
      if ((tid & 7) == 0) frow_s[srow] = fsc;
      // V^T write (vl0/vl1 loaded at tile top)
#pragma unroll
      for (int e = 0; e < 8; ++e) {
        int d0 = vd16 + e, d1 = vd16 + 8 + e;
        vt_s[d0 * 64 + (vj ^ vkey(d0))] = (unsigned short)vl0[e];
        vt_s[d1 * 64 + (vj ^ vkey(d1))] = (unsigned short)vl1[e];
      }
    }
    __syncthreads();   // T4

    // ---- rescale O by frow, PV MFMAs, and stage next tile's K/KR
#pragma unroll
    for (int mi = 0; mi < 2; ++mi) {
#pragma unroll
      for (int r = 0; r < 4; ++r)
        acc_v[mi][r] *= frow_s[mi * 16 + (lane >> 4) * 4 + r];
    }
#pragma unroll
    for (int ks = 0; ks < 2; ++ks) {
      int kb = ks * 32 + (lane >> 4) * 8;
      int vrow = w * 16 + (lane & 15);
      short8v bv = *(const short8v*)&vt_s[vrow * 64 + (kb ^ vkey(vrow))];
#pragma unroll
      for (int mi = 0; mi < 2; ++mi) {
        int prow = mi * 16 + (lane & 15);
        short8v ap = *(const short8v*)&pb_s[prow * 64 + (kb ^ vkey(prow))];
        acc_v[mi] = __builtin_amdgcn_mfma_f32_16x16x32_bf16(ap, bv, acc_v[mi], 0, 0, 0);
      }
    }
    if (jt < 448) {
      int jn = jt + 64;
#pragma unroll
      for (int c = 0; c < 2; ++c) {
        int idx = tid + c * 256;
        int row = idx >> 3, k8 = (idx & 7) * 8;
        *(short8v*)&k_s[row * 72 + k8] =
            *(const short8v*)&qkv[(size_t)((jn + row) * B + b) * 2304 + 768 + n * 64 + k8];
      }
      int u0 = 481 - it + jn;
#pragma unroll
      for (int c = 0; c < 3; ++c) {
        int idx = tid + c * 256;
        int row = idx >> 3, k8 = (idx & 7) * 8;
        *(short8v*)&kr_s[row * 72 + k8] =
            *(const short8v*)&krb[(size_t)(u0 + row) * 768 + n * 64 + k8];
      }
    }
    __syncthreads();   // T1 (next)
  }

  // ---- final row sums -> rinv
  {
    float tot = rsq;
    tot += __shfl_xor(tot, 1, 8);
    tot += __shfl_xor(tot, 2, 8);
    tot += __shfl_xor(tot, 4, 8);
    if ((tid & 7) == 0) rinv_s[srow] = 1.0f / tot;
  }
  __syncthreads();

  // ---- epilogue
#pragma unroll
  for (int mi = 0; mi < 2; ++mi)
#pragma unroll
    for (int r = 0; r < 4; ++r) {
      int row = mi * 16 + (lane >> 4) * 4 + r;
      int d = w * 16 + (lane & 15);
      int t = (it + row) * B + b;
      vec_bf[(size_t)t * D + n * 64 + d] = f2b(acc_v[mi][r] * rinv_s[row]);
    }
}

// ------- fused split-K reduce + bias + residual + layernorm -> h, h_bf --------
template <int P, int HASBIAS>
__global__ __launch_bounds__(256) void add_ln_reduce(const float* __restrict__ part,
                                                     const float* __restrict__ bias,
                                                     float* __restrict__ h,
                                                     unsigned short* __restrict__ h_bf,
                                                     const float* __restrict__ g,
                                                     const float* __restrict__ bi) {
  int t = blockIdx.x;
  int tid = threadIdx.x;
  __shared__ float red[256];
  float vx = 0.f, vy = 0.f, vz = 0.f, vw = 0.f;
  float s = 0.0f;
  int c = tid * 4;
  if (tid < 192) {
    float4 x = {0.f, 0.f, 0.f, 0.f};
#pragma unroll
    for (int p = 0; p < P; ++p) {
      float4 pp = *(const float4*)&part[(size_t)p * NTOK * D + (size_t)t * D + c];
      x.x += pp.x; x.y += pp.y; x.z += pp.z; x.w += pp.w;
    }
    if (HASBIAS) {
      float4 bb = *(const float4*)&bias[c];
      x.x += bb.x; x.y += bb.y; x.z += bb.z; x.w += bb.w;
    }
    float4 hh = *(const float4*)&h[(size_t)t * D + c];
    vx = x.x + hh.x; vy = x.y + hh.y; vz = x.z + hh.z; vw = x.w + hh.w;
    s = vx + vy + vz + vw;
  }
  red[tid] = s;
  __syncthreads();
  for (int st = 128; st > 0; st >>= 1) {
    if (tid < st) red[tid] += red[tid + st];
    __syncthreads();
  }
  float mu = red[0] / (float)D;
  __syncthreads();
  float s2 = 0.0f;
  if (tid < 192) {
    float dx = vx - mu, dy = vy - mu, dz = vz - mu, dw = vw - mu;
    s2 = dx * dx + dy * dy + dz * dz + dw * dw;
  }
  red[tid] = s2;
  __syncthreads();
  for (int st = 128; st > 0; st >>= 1) {
    if (tid < st) red[tid] += red[tid + st];
    __syncthreads();
  }
  float var = red[0] / (float)D;
  float rstd = rsqrtf(var + 1e-3f);
  __syncthreads();
  if (tid < 192) {
    float4 gg = *(const float4*)&g[c];
    float4 bb = *(const float4*)&bi[c];
    float o0 = (vx - mu) * rstd * gg.x + bb.x;
    float o1 = (vy - mu) * rstd * gg.y + bb.y;
    float o2 = (vz - mu) * rstd * gg.z + bb.z;
    float o3 = (vw - mu) * rstd * gg.w + bb.w;
    float4 of = {o0, o1, o2, o3};
    *(float4*)&h[(size_t)t * D + c] = of;
    ushort4 ob;
    ob.x = f2b(o0); ob.y = f2b(o1); ob.z = f2b(o2); ob.w = f2b(o3);
    *(ushort4*)&h_bf[(size_t)t * D + c] = ob;
  }
}

extern "C" void kernel_launch(void* const* d_in, const int* in_sizes, int n_in,
                              void* d_out, int out_size, void* d_ws, size_t ws_size,
                              hipStream_t stream) {
  const int*   inp_k      = (const int*)d_in[0];
  const int*   seg_ids    = (const int*)d_in[1];
  const int*   input_mask = (const int*)d_in[2];
  const float* lut        = (const float*)d_in[3];
  const float* Wq         = (const float*)d_in[4];
  const float* Wk         = (const float*)d_in[5];
  const float* Wv         = (const float*)d_in[6];
  const float* Wr         = (const float*)d_in[7];
  const float* Wo         = (const float*)d_in[8];
  const float* r_w_bias   = (const float*)d_in[9];
  const float* r_r_bias   = (const float*)d_in[10];
  const float* r_s_bias   = (const float*)d_in[11];
  const float* seg_embed  = (const float*)d_in[12];
  const float* ln_attn_g  = (const float*)d_in[13];
  const float* ln_attn_b  = (const float*)d_in[14];
  const float* ln_ff_g    = (const float*)d_in[15];
  const float* ln_ff_b    = (const float*)d_in[16];
  const float* ff_w1      = (const float*)d_in[17];
  const float* ff_b1      = (const float*)d_in[18];
  const float* ff_w2      = (const float*)d_in[19];
  const float* ff_b2      = (const float*)d_in[20];

  float* h = (float*)d_out;
  char* wp = (char*)d_ws;
  auto alloc = [&](size_t bytes) -> void* {
    void* p = (void*)wp;
    wp += (bytes + 255) & ~(size_t)255;
    return p;
  };
  const size_t TOKD = (size_t)NTOK * D;
  const size_t DD = (size_t)D * D;
  const size_t DDI = (size_t)D * DI;
  unsigned short* qkv_bf = (unsigned short*)alloc((size_t)NTOK * 2304 * 2);
  unsigned short* kr_all = (unsigned short*)alloc((size_t)NL * TOKD * 2);
  unsigned short* h_bf   = (unsigned short*)alloc(TOKD * 2);
  unsigned short* r2_bf  = (unsigned short*)alloc(TOKD * 2);
  unsigned short* vec_bf = (unsigned short*)alloc(TOKD * 2);
  unsigned short* ff1_bf = (unsigned short*)alloc((size_t)NTOK * DI * 2);
  float* part = (float*)alloc((size_t)4 * TOKD * 4);
  unsigned short* wqkv_t = (unsigned short*)alloc((size_t)NL * 3 * DD * 2);
  unsigned short* wr_t   = (unsigned short*)alloc((size_t)NL * DD * 2);
  unsigned short* wo_t   = (unsigned short*)alloc((size_t)NL * DD * 2);
  unsigned short* w1_t   = (unsigned short*)alloc((size_t)NL * DDI * 2);
  unsigned short* w2_t   = (unsigned short*)alloc((size_t)NL * DDI * 2);

  prep_all<<<NL * 1872, 256, 0, stream>>>(Wq, Wk, Wv, Wr, Wo, ff_w1, ff_w2,
                                          wqkv_t, wr_t, wo_t, w1_t, w2_t);
  embed_kernel<<<NTOK, 256, 0, stream>>>(inp_k, lut, h, h_bf);
  posemb_kernel<<<2 * S, 384, 0, stream>>>(r2_bf);
  gemm_kr_all<<<NL * 96, 256, 0, stream>>>(r2_bf, wr_t, kr_all);

  for (int l = 0; l < NL; ++l) {
    gemm_qkv<<<288, 256, 0, stream>>>(h_bf, wqkv_t + (size_t)l * 3 * DD, qkv_bf);

    attn_kernel<<<dim3(16, B, H), 256, 0, stream>>>(
        qkv_bf, kr_all + (size_t)l * TOKD, seg_ids, input_mask,
        r_w_bias + (size_t)l * D, r_r_bias + (size_t)l * D,
        r_s_bias + (size_t)l * D, seg_embed + (size_t)l * 2 * H * DH,
        vec_bf);

    gemm_splitk<<<dim3(6, 16, 2), 256, 0, stream>>>(
        vec_bf, wo_t + (size_t)l * DD, part, D, D, 384);
    add_ln_reduce<2, 0><<<NTOK, 256, 0, stream>>>(
        part, nullptr, h, h_bf, ln_attn_g + (size_t)l * D, ln_attn_b + (size_t)l * D);

    gemm_bias<1><<<24 * 16, 256, 0, stream>>>(
        h_bf, w1_t + (size_t)l * DDI, ff_b1 + (size_t)l * DI, ff1_bf, DI, D, 24);

    gemm_splitk<<<dim3(6, 16, 4), 256, 0, stream>>>(
        ff1_bf, w2_t + (size_t)l * DDI, part, D, DI, 768);
    add_ln_reduce<4, 1><<<NTOK, 256, 0, stream>>>(
        part, ff_b2 + (size_t)l * D, h, h_bf, ln_ff_g + (size_t)l * D, ln_ff_b + (size_t)l * D);
  }
}